// Round 1
// baseline (6552.513 us; speedup 1.0000x reference)
//
#include <hip/hip_runtime.h>
#include <cmath>

#define S_ 4
#define N_ 50000
#define C_ 256
#define E_ 800000
#define L_ 3
#define EPS_ 1e-5f

// ---------------------------------------------------------------------------
// GEMM: out[M,Nn] = A[M,K] * op(B) (+ bias per column)
// NT=false: B is [K,Nn] row-major. NT=true: B is [Nn,K] row-major (use B^T).
// 64x64 tile, BK=16, 256 threads, 4x4 per thread.
// ---------------------------------------------------------------------------
template<bool NT>
__global__ __launch_bounds__(256) void gemm_f32(
    const float* __restrict__ A, const float* __restrict__ B,
    const float* __restrict__ bias, float* __restrict__ Cout,
    int M, int Nn, int K)
{
  __shared__ float As[16][68];
  __shared__ float Bs[16][68];
  const int bm = blockIdx.x * 64;
  const int bn = blockIdx.y * 64;
  const int tid = threadIdx.x;
  const int la_i = tid >> 2;            // 0..63
  const int la_k = (tid & 3) << 2;      // 0,4,8,12
  const int i0 = (tid >> 4) << 2;       // 0..60
  const int j0 = (tid & 15) << 2;       // 0..60
  float acc[4][4] = {};

  for (int k0 = 0; k0 < K; k0 += 16) {
    { // A tile (transpose into LDS)
      int arow = bm + la_i;
      float4 f = make_float4(0.f, 0.f, 0.f, 0.f);
      if (arow < M) f = *(const float4*)&A[(size_t)arow * K + k0 + la_k];
      As[la_k + 0][la_i] = f.x; As[la_k + 1][la_i] = f.y;
      As[la_k + 2][la_i] = f.z; As[la_k + 3][la_i] = f.w;
    }
    if (NT) {
      int brow = bn + la_i;
      float4 f = *(const float4*)&B[(size_t)brow * K + k0 + la_k];
      Bs[la_k + 0][la_i] = f.x; Bs[la_k + 1][la_i] = f.y;
      Bs[la_k + 2][la_i] = f.z; Bs[la_k + 3][la_i] = f.w;
    } else {
      int bk = tid >> 4;                // 0..15
      int bj = (tid & 15) << 2;         // 0..60
      float4 f = *(const float4*)&B[(size_t)(k0 + bk) * Nn + bn + bj];
      *(float4*)&Bs[bk][bj] = f;
    }
    __syncthreads();
    #pragma unroll
    for (int kk = 0; kk < 16; ++kk) {
      float4 a = *(const float4*)&As[kk][i0];
      float4 b = *(const float4*)&Bs[kk][j0];
      float av[4] = {a.x, a.y, a.z, a.w};
      float bv[4] = {b.x, b.y, b.z, b.w};
      #pragma unroll
      for (int qi = 0; qi < 4; ++qi)
        #pragma unroll
        for (int qj = 0; qj < 4; ++qj)
          acc[qi][qj] = fmaf(av[qi], bv[qj], acc[qi][qj]);
    }
    __syncthreads();
  }

  #pragma unroll
  for (int qi = 0; qi < 4; ++qi) {
    int row = bm + i0 + qi;
    if (row < M) {
      float b0 = bias ? bias[bn + j0 + 0] : 0.f;
      float b1 = bias ? bias[bn + j0 + 1] : 0.f;
      float b2 = bias ? bias[bn + j0 + 2] : 0.f;
      float b3 = bias ? bias[bn + j0 + 3] : 0.f;
      float4 o = make_float4(acc[qi][0] + b0, acc[qi][1] + b1,
                             acc[qi][2] + b2, acc[qi][3] + b3);
      *(float4*)&Cout[(size_t)row * Nn + bn + j0] = o;
    }
  }
}

// ---------------------------------------------------------------------------
// Per-snapshot graph preprocessing
// ---------------------------------------------------------------------------
__global__ void init_deg_kernel(float* __restrict__ deg, int* __restrict__ cnt,
                                int* __restrict__ fill, int n) {
  int i = blockIdx.x * blockDim.x + threadIdx.x;
  if (i < n) { deg[i] = 1.0f; cnt[i] = 0; fill[i] = 0; }
}

__global__ void deg_count_kernel(const int* __restrict__ col,
                                 const float* __restrict__ ew,
                                 float* __restrict__ deg, int* __restrict__ cnt, int E) {
  int e = blockIdx.x * blockDim.x + threadIdx.x;
  if (e < E) {
    int c = col[e];
    atomicAdd(&deg[c], ew[e]);
    atomicAdd(&cnt[c], 1);
  }
}

__global__ void dinv_kernel(const float* __restrict__ deg, float* __restrict__ dinv, int n) {
  int i = blockIdx.x * blockDim.x + threadIdx.x;
  if (i < n) {
    float d = deg[i];
    dinv[i] = (d > 0.f) ? rsqrtf(fmaxf(d, 1e-12f)) : 0.f;
  }
}

// single-block exclusive scan over cnt -> rowptr (n up to ~50k)
__global__ void scan_kernel(const int* __restrict__ cnt, int* __restrict__ rowptr, int n) {
  __shared__ int sdata[1024];
  __shared__ int s_carry;
  int tid = threadIdx.x;
  if (tid == 0) s_carry = 0;
  __syncthreads();
  for (int base = 0; base < n; base += 1024) {
    int i = base + tid;
    int v = (i < n) ? cnt[i] : 0;
    sdata[tid] = v;
    __syncthreads();
    int acc = v;
    for (int off = 1; off < 1024; off <<= 1) {
      int t = (tid >= off) ? sdata[tid - off] : 0;
      __syncthreads();
      acc += t;
      sdata[tid] = acc;
      __syncthreads();
    }
    int carry = s_carry;
    if (i < n) rowptr[i] = carry + acc - v;   // exclusive
    __syncthreads();
    if (tid == 1023) s_carry = carry + acc;   // chunk total
    __syncthreads();
  }
  if (tid == 0) rowptr[n] = s_carry;
}

__global__ void csr_fill_kernel(const int* __restrict__ row, const int* __restrict__ col,
                                const float* __restrict__ ew, const float* __restrict__ dinv,
                                const int* __restrict__ rowptr, int* __restrict__ fill,
                                int* __restrict__ src_sorted, float* __restrict__ norm_sorted,
                                int E) {
  int e = blockIdx.x * blockDim.x + threadIdx.x;
  if (e < E) {
    int c = col[e];
    int r = row[e];
    int pos = rowptr[c] + atomicAdd(&fill[c], 1);
    src_sorted[pos] = r;
    norm_sorted[pos] = dinv[r] * ew[e] * dinv[c];
  }
}

// ---------------------------------------------------------------------------
// Fused: out[n,:] = ReLU(LN( self + sum_in_edges norm*hW[src,:] + b_gcn ))
// one block (256 threads) per node; thread = channel
// ---------------------------------------------------------------------------
__global__ __launch_bounds__(256) void spmm_ln_relu_kernel(
    const float* __restrict__ hW, const int* __restrict__ rowptr,
    const int* __restrict__ src, const float* __restrict__ normv,
    const float* __restrict__ dinv, const float* __restrict__ bgcn,
    const float* __restrict__ lnsc, const float* __restrict__ lnbi,
    float* __restrict__ out)
{
  int n = blockIdx.x;
  int c = threadIdx.x;
  float dv = dinv[n];
  float acc = dv * dv * hW[(size_t)n * C_ + c];   // self loop (ew = 1)
  int e0 = rowptr[n], e1 = rowptr[n + 1];
  for (int e = e0; e < e1; ++e) {
    acc = fmaf(normv[e], hW[(size_t)src[e] * C_ + c], acc);
  }
  acc += bgcn[c];

  // block reduce: sum and sum-of-squares over 256 channels
  float s1 = acc, s2 = acc * acc;
  #pragma unroll
  for (int off = 32; off > 0; off >>= 1) {
    s1 += __shfl_down(s1, off);
    s2 += __shfl_down(s2, off);
  }
  __shared__ float r1[4], r2[4];
  int wid = threadIdx.x >> 6, lane = threadIdx.x & 63;
  if (lane == 0) { r1[wid] = s1; r2[wid] = s2; }
  __syncthreads();
  float t1 = r1[0] + r1[1] + r1[2] + r1[3];
  float t2 = r2[0] + r2[1] + r2[2] + r2[3];
  float mu = t1 * (1.0f / C_);
  float var = t2 * (1.0f / C_) - mu * mu;
  float inv = rsqrtf(var + EPS_);
  float v = (acc - mu) * inv * lnsc[c] + lnbi[c];
  out[(size_t)n * C_ + c] = fmaxf(v, 0.f);
}

// ---------------------------------------------------------------------------
// GRU pointwise gates for a row chunk
// ---------------------------------------------------------------------------
__global__ void gru_pointwise_kernel(const float* __restrict__ gi,
                                     const float* __restrict__ gh,
                                     float* __restrict__ h, int rows) {
  int idx = blockIdx.x * blockDim.x + threadIdx.x;
  if (idx < rows * C_) {
    int i = idx / C_, c = idx % C_;
    const float* gir = gi + (size_t)i * 3 * C_;
    const float* ghr = gh + (size_t)i * 3 * C_;
    float ir = gir[c],        hr = ghr[c];
    float iz = gir[C_ + c],   hz = ghr[C_ + c];
    float in_ = gir[2 * C_ + c], hn = ghr[2 * C_ + c];
    float r = 1.f / (1.f + expf(-(ir + hr)));
    float z = 1.f / (1.f + expf(-(iz + hz)));
    float nn = tanhf(in_ + r * hn);
    float hp = h[idx];
    h[idx] = (1.f - z) * nn + z * hp;
  }
}

// ---------------------------------------------------------------------------
extern "C" void kernel_launch(void* const* d_in, const int* in_sizes, int n_in,
                              void* d_out, int out_size, void* d_ws, size_t ws_size,
                              hipStream_t stream) {
  const float* x        = (const float*)d_in[0];   // [S,N,C]
  const int*   edge_idx = (const int*)d_in[1];     // [S,2,E]
  const float* edge_w   = (const float*)d_in[2];   // [S,E]
  const float* W_gcn    = (const float*)d_in[3];   // [L,C,C]
  const float* b_gcn    = (const float*)d_in[4];   // [L,C]
  const float* ln_scale = (const float*)d_in[5];   // [L,C]
  const float* ln_bias  = (const float*)d_in[6];   // [L,C]
  const float* w_ih     = (const float*)d_in[7];   // [3C,C]
  const float* w_hh     = (const float*)d_in[8];   // [3C,C]
  const float* b_ih     = (const float*)d_in[9];   // [3C]
  const float* b_hh     = (const float*)d_in[10];  // [3C]
  float* h_out = (float*)d_out;                    // [N,C] hidden state

  // workspace carve (256B aligned)
  char* p = (char*)d_ws;
  auto carve = [&](size_t bytes) -> void* {
    void* r = (void*)p;
    p += (bytes + 255) & ~(size_t)255;
    return r;
  };
  float* deg         = (float*)carve(N_ * 4);
  float* dinv        = (float*)carve(N_ * 4);
  int*   cnt         = (int*)carve(N_ * 4);
  int*   fill        = (int*)carve(N_ * 4);
  int*   rowptr      = (int*)carve((N_ + 1) * 4);
  int*   src_sorted  = (int*)carve((size_t)E_ * 4);
  float* norm_sorted = (float*)carve((size_t)E_ * 4);
  float* hW          = (float*)carve((size_t)N_ * C_ * 4);  // also GRU gi chunk
  float* fA          = (float*)carve((size_t)N_ * C_ * 4);
  float* fB          = (float*)carve((size_t)N_ * C_ * 4);  // also GRU gh chunk

  hipMemsetAsync(d_out, 0, (size_t)N_ * C_ * 4, stream);

  const int TB = 256;
  const int gN = (N_ + TB - 1) / TB;
  const int gE = (E_ + TB - 1) / TB;
  const int NCH = 12500;                       // GRU row chunk (4 chunks)

  for (int s = 0; s < S_; ++s) {
    const int* row = edge_idx + (size_t)s * 2 * E_;
    const int* col = row + E_;
    const float* ew = edge_w + (size_t)s * E_;

    init_deg_kernel<<<gN, TB, 0, stream>>>(deg, cnt, fill, N_);
    deg_count_kernel<<<gE, TB, 0, stream>>>(col, ew, deg, cnt, E_);
    dinv_kernel<<<gN, TB, 0, stream>>>(deg, dinv, N_);
    scan_kernel<<<1, 1024, 0, stream>>>(cnt, rowptr, N_);
    csr_fill_kernel<<<gE, TB, 0, stream>>>(row, col, ew, dinv, rowptr, fill,
                                           src_sorted, norm_sorted, E_);

    const float* hin = x + (size_t)s * N_ * C_;
    float* feat = fA;
    for (int l = 0; l < L_; ++l) {
      float* fout = (l == 0) ? fA : ((l == 1) ? fB : fA);
      dim3 grid((N_ + 63) / 64, C_ / 64);
      gemm_f32<false><<<grid, 256, 0, stream>>>(hin, W_gcn + (size_t)l * C_ * C_,
                                                nullptr, hW, N_, C_, C_);
      spmm_ln_relu_kernel<<<N_, 256, 0, stream>>>(hW, rowptr, src_sorted, norm_sorted,
                                                  dinv, b_gcn + l * C_,
                                                  ln_scale + l * C_, ln_bias + l * C_,
                                                  fout);
      hin = fout;
      feat = fout;
    }

    // GRU step on feat (chunked over rows; gi->hW, gh->fB scratch)
    for (int k = 0; k < N_ / NCH; ++k) {
      const float* xoff = feat + (size_t)k * NCH * C_;
      float* hoff = h_out + (size_t)k * NCH * C_;
      dim3 grid((NCH + 63) / 64, (3 * C_) / 64);
      gemm_f32<true><<<grid, 256, 0, stream>>>(xoff, w_ih, b_ih, hW, NCH, 3 * C_, C_);
      gemm_f32<true><<<grid, 256, 0, stream>>>(hoff, w_hh, b_hh, fB, NCH, 3 * C_, C_);
      gru_pointwise_kernel<<<(NCH * C_ + TB - 1) / TB, TB, 0, stream>>>(hW, fB, hoff, NCH);
    }
  }
}

// Round 2
// 3495.200 us; speedup vs baseline: 1.8747x; 1.8747x over previous
//
#include <hip/hip_runtime.h>
#include <cmath>

#define S_ 4
#define N_ 50000
#define C_ 256
#define E_ 800000
#define L_ 3
#define EPS_ 1e-5f

typedef __attribute__((ext_vector_type(8))) short bf16x8;
typedef __attribute__((ext_vector_type(4))) float f32x4;

__device__ __forceinline__ float bf2f(unsigned short s) {
  return __uint_as_float(((unsigned)s) << 16);
}
__device__ __forceinline__ unsigned short f2bf(float f) {
  unsigned u = __float_as_uint(f);
  return (unsigned short)((u + 0x7fffu + ((u >> 16) & 1u)) >> 16);  // RNE
}

__device__ __forceinline__ void gload_lds16(const void* g, void* l) {
  __builtin_amdgcn_global_load_lds(
      (const __attribute__((address_space(1))) unsigned int*)g,
      (__attribute__((address_space(3))) unsigned int*)l, 16, 0, 0);
}

// ---------------------------------------------------------------------------
// bf16 MFMA GEMM: Cout[M,Nn] = A[M,K](bf16) * Bt[Nn,K]^T(bf16) (+bias[col])
// 128x128 tile, BK=32, 256 threads (4 waves 2x2), 4x4 16x16 frags per wave.
// LDS staged via global_load_lds w16 with XOR granule swizzle (2-way max).
// Requires: K%32==0, Nn%128==0. M arbitrary (row clamp on load, guard store).
// ---------------------------------------------------------------------------
template<typename OutT>
__global__ __launch_bounds__(256) void gemm_bf16_kernel(
    const unsigned short* __restrict__ A, const unsigned short* __restrict__ Bt,
    const float* __restrict__ bias, OutT* __restrict__ Cout,
    int M, int Nn, int K)
{
  __shared__ alignas(16) unsigned short As[128 * 32];
  __shared__ alignas(16) unsigned short Bs[128 * 32];
  const int tid = threadIdx.x;
  const int lane = tid & 63;
  const int wid = tid >> 6;
  const int wr = wid >> 1, wc = wid & 1;
  const int bm = blockIdx.x * 128, bn = blockIdx.y * 128;
  const int l15 = lane & 15, l4 = lane >> 4;

  f32x4 acc[4][4] = {};

  // fragment LDS element offsets (swizzled)
  int offA[4], offB[4];
  #pragma unroll
  for (int mi = 0; mi < 4; ++mi) {
    int ra = wr * 64 + mi * 16 + l15;
    offA[mi] = ra * 32 + ((l4 ^ ((ra >> 1) & 3)) << 3);
    int rb = wc * 64 + mi * 16 + l15;
    offB[mi] = rb * 32 + ((l4 ^ ((rb >> 1) & 3)) << 3);
  }
  const int rs = tid >> 2;       // staging row (t=0) / +64 (t=1)
  const int gs = tid & 3;        // granule within row

  for (int k0 = 0; k0 < K; k0 += 32) {
    __syncthreads();  // previous iter's reads done before overwrite
    #pragma unroll
    for (int t = 0; t < 2; ++t) {
      int r = rs + t * 64;
      int q = gs ^ ((r >> 1) & 3);
      int arow = bm + r; if (arow >= M) arow = M - 1;
      gload_lds16(&A[(size_t)arow * K + k0 + q * 8], &As[(t * 256 + tid) * 8]);
      int brow = bn + r;
      gload_lds16(&Bt[(size_t)brow * K + k0 + q * 8], &Bs[(t * 256 + tid) * 8]);
    }
    __syncthreads();

    bf16x8 af[4], bfr[4];
    #pragma unroll
    for (int mi = 0; mi < 4; ++mi) af[mi] = *(const bf16x8*)&As[offA[mi]];
    #pragma unroll
    for (int ni = 0; ni < 4; ++ni) bfr[ni] = *(const bf16x8*)&Bs[offB[ni]];
    #pragma unroll
    for (int mi = 0; mi < 4; ++mi)
      #pragma unroll
      for (int ni = 0; ni < 4; ++ni)
        acc[mi][ni] = __builtin_amdgcn_mfma_f32_16x16x32_bf16(
            af[mi], bfr[ni], acc[mi][ni], 0, 0, 0);
  }

  #pragma unroll
  for (int mi = 0; mi < 4; ++mi) {
    int rowb = bm + wr * 64 + mi * 16 + l4 * 4;
    #pragma unroll
    for (int ni = 0; ni < 4; ++ni) {
      int col = bn + wc * 64 + ni * 16 + l15;
      float bv = bias ? bias[col] : 0.f;
      #pragma unroll
      for (int r = 0; r < 4; ++r) {
        int row = rowb + r;
        if (row < M) {
          float v = acc[mi][ni][r] + bv;
          if constexpr (sizeof(OutT) == 2)
            Cout[(size_t)row * Nn + col] = (OutT)f2bf(v);
          else
            Cout[(size_t)row * Nn + col] = (OutT)v;
        }
      }
    }
  }
}

// ---------------------------------------------------------------------------
// Weight prep (once per launch)
// ---------------------------------------------------------------------------
__global__ void prep_wgcn_kernel(const float* __restrict__ W, unsigned short* __restrict__ Wt) {
  int i = blockIdx.x * blockDim.x + threadIdx.x;  // l*C*C + n*C + k
  if (i < L_ * C_ * C_) {
    int l = i / (C_ * C_);
    int rem = i - l * C_ * C_;
    int nn = rem >> 8, k = rem & 255;
    Wt[i] = f2bf(W[l * C_ * C_ + k * C_ + nn]);
  }
}
__global__ void prep_cast_kernel(const float* __restrict__ W, unsigned short* __restrict__ Wt, int n) {
  int i = blockIdx.x * blockDim.x + threadIdx.x;
  if (i < n) Wt[i] = f2bf(W[i]);
}
__global__ void quant_kernel(const float* __restrict__ in, unsigned short* __restrict__ out, int n4) {
  int i = blockIdx.x * blockDim.x + threadIdx.x;
  if (i < n4) {
    float4 v = ((const float4*)in)[i];
    ushort4 q;
    q.x = f2bf(v.x); q.y = f2bf(v.y); q.z = f2bf(v.z); q.w = f2bf(v.w);
    *(ushort4*)&out[i * 4] = q;
  }
}

// ---------------------------------------------------------------------------
// Per-snapshot graph preprocessing (fp32, unchanged)
// ---------------------------------------------------------------------------
__global__ void init_deg_kernel(float* __restrict__ deg, int* __restrict__ cnt,
                                int* __restrict__ fill, int n) {
  int i = blockIdx.x * blockDim.x + threadIdx.x;
  if (i < n) { deg[i] = 1.0f; cnt[i] = 0; fill[i] = 0; }
}
__global__ void deg_count_kernel(const int* __restrict__ col, const float* __restrict__ ew,
                                 float* __restrict__ deg, int* __restrict__ cnt, int E) {
  int e = blockIdx.x * blockDim.x + threadIdx.x;
  if (e < E) {
    int c = col[e];
    atomicAdd(&deg[c], ew[e]);
    atomicAdd(&cnt[c], 1);
  }
}
__global__ void dinv_kernel(const float* __restrict__ deg, float* __restrict__ dinv, int n) {
  int i = blockIdx.x * blockDim.x + threadIdx.x;
  if (i < n) {
    float d = deg[i];
    dinv[i] = (d > 0.f) ? rsqrtf(fmaxf(d, 1e-12f)) : 0.f;
  }
}
__global__ void scan_kernel(const int* __restrict__ cnt, int* __restrict__ rowptr, int n) {
  __shared__ int sdata[1024];
  __shared__ int s_carry;
  int tid = threadIdx.x;
  if (tid == 0) s_carry = 0;
  __syncthreads();
  for (int base = 0; base < n; base += 1024) {
    int i = base + tid;
    int v = (i < n) ? cnt[i] : 0;
    sdata[tid] = v;
    __syncthreads();
    int acc = v;
    for (int off = 1; off < 1024; off <<= 1) {
      int t = (tid >= off) ? sdata[tid - off] : 0;
      __syncthreads();
      acc += t;
      sdata[tid] = acc;
      __syncthreads();
    }
    int carry = s_carry;
    if (i < n) rowptr[i] = carry + acc - v;
    __syncthreads();
    if (tid == 1023) s_carry = carry + acc;
    __syncthreads();
  }
  if (tid == 0) rowptr[n] = s_carry;
}
__global__ void csr_fill_kernel(const int* __restrict__ row, const int* __restrict__ col,
                                const float* __restrict__ ew, const float* __restrict__ dinv,
                                const int* __restrict__ rowptr, int* __restrict__ fill,
                                int* __restrict__ src_sorted, float* __restrict__ norm_sorted, int E) {
  int e = blockIdx.x * blockDim.x + threadIdx.x;
  if (e < E) {
    int c = col[e];
    int r = row[e];
    int pos = rowptr[c] + atomicAdd(&fill[c], 1);
    src_sorted[pos] = r;
    norm_sorted[pos] = dinv[r] * ew[e] * dinv[c];
  }
}

// ---------------------------------------------------------------------------
// Fused: out[n,:] = bf16(ReLU(LN( self + sum norm*hW[src,:] + b_gcn )))
// hW is bf16. Edge (src,norm) staged through LDS in chunks of 256.
// ---------------------------------------------------------------------------
__global__ __launch_bounds__(256) void spmm_ln_relu_kernel(
    const unsigned short* __restrict__ hW, const int* __restrict__ rowptr,
    const int* __restrict__ src, const float* __restrict__ normv,
    const float* __restrict__ dinv, const float* __restrict__ bgcn,
    const float* __restrict__ lnsc, const float* __restrict__ lnbi,
    unsigned short* __restrict__ out)
{
  __shared__ int s_src[256];
  __shared__ float s_nrm[256];
  int n = blockIdx.x;
  int c = threadIdx.x;
  float dv = dinv[n];
  float acc = dv * dv * bf2f(hW[(size_t)n * C_ + c]);  // self loop (ew=1)
  int e0 = rowptr[n], e1 = rowptr[n + 1];
  for (int base = e0; base < e1; base += 256) {
    int ee = base + c;
    if (ee < e1) { s_src[c] = src[ee]; s_nrm[c] = normv[ee]; }
    __syncthreads();
    int cnt = min(256, e1 - base);
    for (int j = 0; j < cnt; ++j)
      acc = fmaf(s_nrm[j], bf2f(hW[(size_t)s_src[j] * C_ + c]), acc);
    __syncthreads();
  }
  acc += bgcn[c];

  float s1 = acc, s2 = acc * acc;
  #pragma unroll
  for (int off = 32; off > 0; off >>= 1) {
    s1 += __shfl_down(s1, off);
    s2 += __shfl_down(s2, off);
  }
  __shared__ float r1[4], r2[4];
  int wid = threadIdx.x >> 6, lane = threadIdx.x & 63;
  if (lane == 0) { r1[wid] = s1; r2[wid] = s2; }
  __syncthreads();
  float t1 = r1[0] + r1[1] + r1[2] + r1[3];
  float t2 = r2[0] + r2[1] + r2[2] + r2[3];
  float mu = t1 * (1.0f / C_);
  float var = t2 * (1.0f / C_) - mu * mu;
  float inv = rsqrtf(var + EPS_);
  float v = (acc - mu) * inv * lnsc[c] + lnbi[c];
  out[(size_t)n * C_ + c] = f2bf(fmaxf(v, 0.f));
}

// ---------------------------------------------------------------------------
// GRU pointwise: h = (1-z)*n + z*h ; writes fp32 h (d_out) + bf16 hq
// ---------------------------------------------------------------------------
__global__ void gru_pointwise_kernel(const float* __restrict__ gi, const float* __restrict__ gh,
                                     float* __restrict__ h, unsigned short* __restrict__ hq, int rows) {
  int idx = blockIdx.x * blockDim.x + threadIdx.x;
  if (idx >= rows * 64) return;
  int i = idx >> 6, c4 = (idx & 63) << 2;
  const float* gir = gi + (size_t)i * 768;
  const float* ghr = gh + (size_t)i * 768;
  float4 ir = *(const float4*)&gir[c4];
  float4 iz = *(const float4*)&gir[256 + c4];
  float4 in_ = *(const float4*)&gir[512 + c4];
  float4 hr = *(const float4*)&ghr[c4];
  float4 hz = *(const float4*)&ghr[256 + c4];
  float4 hn = *(const float4*)&ghr[512 + c4];
  float4 hp = *(const float4*)&h[(size_t)i * 256 + c4];
  float4 ho;
  ushort4 hqo;
  const float* pir = (const float*)&ir; const float* piz = (const float*)&iz;
  const float* pin = (const float*)&in_; const float* phr = (const float*)&hr;
  const float* phz = (const float*)&hz; const float* phn = (const float*)&hn;
  const float* php = (const float*)&hp;
  float* pho = (float*)&ho; unsigned short* phq = (unsigned short*)&hqo;
  #pragma unroll
  for (int j = 0; j < 4; ++j) {
    float r = 1.f / (1.f + expf(-(pir[j] + phr[j])));
    float z = 1.f / (1.f + expf(-(piz[j] + phz[j])));
    float nn = tanhf(pin[j] + r * phn[j]);
    float hv = (1.f - z) * nn + z * php[j];
    pho[j] = hv;
    phq[j] = f2bf(hv);
  }
  *(float4*)&h[(size_t)i * 256 + c4] = ho;
  *(ushort4*)&hq[(size_t)i * 256 + c4] = hqo;
}

// ---------------------------------------------------------------------------
extern "C" void kernel_launch(void* const* d_in, const int* in_sizes, int n_in,
                              void* d_out, int out_size, void* d_ws, size_t ws_size,
                              hipStream_t stream) {
  const float* x        = (const float*)d_in[0];
  const int*   edge_idx = (const int*)d_in[1];
  const float* edge_w   = (const float*)d_in[2];
  const float* W_gcn    = (const float*)d_in[3];
  const float* b_gcn    = (const float*)d_in[4];
  const float* ln_scale = (const float*)d_in[5];
  const float* ln_bias  = (const float*)d_in[6];
  const float* w_ih     = (const float*)d_in[7];
  const float* w_hh     = (const float*)d_in[8];
  const float* b_ih     = (const float*)d_in[9];
  const float* b_hh     = (const float*)d_in[10];
  float* h_out = (float*)d_out;

  char* p = (char*)d_ws;
  auto carve = [&](size_t bytes) -> void* {
    void* r = (void*)p;
    p += (bytes + 255) & ~(size_t)255;
    return r;
  };
  float* deg         = (float*)carve(N_ * 4);
  float* dinv        = (float*)carve(N_ * 4);
  int*   cnt         = (int*)carve(N_ * 4);
  int*   fill        = (int*)carve(N_ * 4);
  int*   rowptr      = (int*)carve((N_ + 1) * 4);
  int*   src_sorted  = (int*)carve((size_t)E_ * 4);
  float* norm_sorted = (float*)carve((size_t)E_ * 4);
  unsigned short* wt_gcn = (unsigned short*)carve((size_t)L_ * C_ * C_ * 2);
  unsigned short* wih_bf = (unsigned short*)carve((size_t)768 * C_ * 2);
  unsigned short* whh_bf = (unsigned short*)carve((size_t)768 * C_ * 2);
  unsigned short* xq = (unsigned short*)carve((size_t)N_ * C_ * 2);  // also fB
  unsigned short* hW = (unsigned short*)carve((size_t)N_ * C_ * 2);
  unsigned short* fA = (unsigned short*)carve((size_t)N_ * C_ * 2);
  unsigned short* hq = (unsigned short*)carve((size_t)N_ * C_ * 2);

  size_t fixed = (size_t)(p - (char*)d_ws);
  int NCH = 12500;
  if (fixed + 2 * (size_t)12500 * 768 * 4 > ws_size) NCH = 6250;
  if (fixed + 2 * (size_t)6250 * 768 * 4 > ws_size) NCH = 3125;
  float* gi = (float*)carve((size_t)NCH * 768 * 4);
  float* gh = (float*)carve((size_t)NCH * 768 * 4);

  hipMemsetAsync(d_out, 0, (size_t)N_ * C_ * 4, stream);
  hipMemsetAsync(hq, 0, (size_t)N_ * C_ * 2, stream);

  const int TB = 256;
  const int gN = (N_ + TB - 1) / TB;
  const int gE = (E_ + TB - 1) / TB;

  prep_wgcn_kernel<<<(L_ * C_ * C_ + TB - 1) / TB, TB, 0, stream>>>(W_gcn, wt_gcn);
  prep_cast_kernel<<<(768 * C_ + TB - 1) / TB, TB, 0, stream>>>(w_ih, wih_bf, 768 * C_);
  prep_cast_kernel<<<(768 * C_ + TB - 1) / TB, TB, 0, stream>>>(w_hh, whh_bf, 768 * C_);

  for (int s = 0; s < S_; ++s) {
    const int* row = edge_idx + (size_t)s * 2 * E_;
    const int* col = row + E_;
    const float* ew = edge_w + (size_t)s * E_;

    quant_kernel<<<(N_ * C_ / 4 + TB - 1) / TB, TB, 0, stream>>>(
        x + (size_t)s * N_ * C_, xq, N_ * C_ / 4);

    init_deg_kernel<<<gN, TB, 0, stream>>>(deg, cnt, fill, N_);
    deg_count_kernel<<<gE, TB, 0, stream>>>(col, ew, deg, cnt, E_);
    dinv_kernel<<<gN, TB, 0, stream>>>(deg, dinv, N_);
    scan_kernel<<<1, 1024, 0, stream>>>(cnt, rowptr, N_);
    csr_fill_kernel<<<gE, TB, 0, stream>>>(row, col, ew, dinv, rowptr, fill,
                                           src_sorted, norm_sorted, E_);

    // GCN layers: xq -> fA -> xq -> fA  (input buffer reused as ping-pong)
    const unsigned short* hin = xq;
    unsigned short* feat = fA;
    for (int l = 0; l < L_; ++l) {
      unsigned short* fout = (l == 1) ? xq : fA;
      dim3 grid((N_ + 127) / 128, C_ / 128);
      gemm_bf16_kernel<unsigned short><<<grid, 256, 0, stream>>>(
          hin, wt_gcn + (size_t)l * C_ * C_, nullptr, hW, N_, C_, C_);
      spmm_ln_relu_kernel<<<N_, 256, 0, stream>>>(hW, rowptr, src_sorted, norm_sorted,
                                                  dinv, b_gcn + l * C_,
                                                  ln_scale + l * C_, ln_bias + l * C_,
                                                  fout);
      hin = fout;
      feat = fout;
    }

    // GRU step (chunked rows)
    for (int k = 0; k < N_ / NCH; ++k) {
      const unsigned short* xoff = feat + (size_t)k * NCH * C_;
      const unsigned short* hoff_q = hq + (size_t)k * NCH * C_;
      float* hoff = h_out + (size_t)k * NCH * C_;
      unsigned short* hqoff = hq + (size_t)k * NCH * C_;
      dim3 grid((NCH + 127) / 128, 768 / 128);
      gemm_bf16_kernel<float><<<grid, 256, 0, stream>>>(xoff, wih_bf, b_ih, gi, NCH, 768, C_);
      gemm_bf16_kernel<float><<<grid, 256, 0, stream>>>(hoff_q, whh_bf, b_hh, gh, NCH, 768, C_);
      gru_pointwise_kernel<<<(NCH * 64 + TB - 1) / TB, TB, 0, stream>>>(gi, gh, hoff, hqoff, NCH);
    }
  }
}

// Round 3
// 3148.118 us; speedup vs baseline: 2.0814x; 1.1103x over previous
//
#include <hip/hip_runtime.h>
#include <cmath>

#define S_ 4
#define N_ 50000
#define C_ 256
#define E_ 800000
#define L_ 3
#define EPS_ 1e-5f

typedef __attribute__((ext_vector_type(8))) short bf16x8;
typedef __attribute__((ext_vector_type(4))) float f32x4;

__device__ __forceinline__ float bf2f(unsigned short s) {
  return __uint_as_float(((unsigned)s) << 16);
}
__device__ __forceinline__ unsigned short f2bf(float f) {
  unsigned u = __float_as_uint(f);
  return (unsigned short)((u + 0x7fffu + ((u >> 16) & 1u)) >> 16);  // RNE
}

__device__ __forceinline__ void gload_lds16(const void* g, void* l) {
  __builtin_amdgcn_global_load_lds(
      (const __attribute__((address_space(1))) unsigned int*)g,
      (__attribute__((address_space(3))) unsigned int*)l, 16, 0, 0);
}

// ---------------------------------------------------------------------------
// bf16 MFMA GEMM: Cout[M,Nn] = A[M,K](bf16) * Bt[Nn,K]^T(bf16) (+bias[col])
// 128x128 tile, BK=32, 256 threads (4 waves 2x2), 4x4 16x16 frags per wave.
// 2-phase double-buffered LDS (stage next before compute, 1 barrier/K-step).
// Requires: K%32==0, Nn%128==0. M arbitrary (row clamp on load, guard store).
// ---------------------------------------------------------------------------
template<typename OutT>
__global__ __launch_bounds__(256) void gemm_bf16_kernel(
    const unsigned short* __restrict__ A, const unsigned short* __restrict__ Bt,
    const float* __restrict__ bias, OutT* __restrict__ Cout,
    int M, int Nn, int K)
{
  __shared__ alignas(16) unsigned short As[2][128 * 32];
  __shared__ alignas(16) unsigned short Bs[2][128 * 32];
  const int tid = threadIdx.x;
  const int lane = tid & 63;
  const int wid = tid >> 6;
  const int wr = wid >> 1, wc = wid & 1;
  const int bm = blockIdx.x * 128, bn = blockIdx.y * 128;
  const int l15 = lane & 15, l4 = lane >> 4;

  f32x4 acc[4][4] = {};

  // fragment LDS element offsets (XOR granule swizzle, 2-way max = free)
  int offA[4], offB[4];
  #pragma unroll
  for (int mi = 0; mi < 4; ++mi) {
    int ra = wr * 64 + mi * 16 + l15;
    offA[mi] = ra * 32 + ((l4 ^ ((ra >> 1) & 3)) << 3);
    int rb = wc * 64 + mi * 16 + l15;
    offB[mi] = rb * 32 + ((l4 ^ ((rb >> 1) & 3)) << 3);
  }
  const int rs = tid >> 2;       // staging row (t=0) / +64 (t=1)
  const int gs = tid & 3;        // granule within row

  auto stage = [&](int buf, int k0) {
    #pragma unroll
    for (int t2 = 0; t2 < 2; ++t2) {
      int r = rs + t2 * 64;
      int q = gs ^ ((r >> 1) & 3);
      int arow = bm + r; if (arow >= M) arow = M - 1;
      gload_lds16(&A[(size_t)arow * K + k0 + q * 8], &As[buf][(t2 * 256 + tid) * 8]);
      int brow = bn + r;
      gload_lds16(&Bt[(size_t)brow * K + k0 + q * 8], &Bs[buf][(t2 * 256 + tid) * 8]);
    }
  };

  const int nt = K >> 5;
  stage(0, 0);
  asm volatile("s_waitcnt vmcnt(0)" ::: "memory");
  __syncthreads();

  int cur = 0;
  for (int t = 0; t < nt; ++t) {
    if (t + 1 < nt) stage(cur ^ 1, (t + 1) * 32);   // issue next-tile loads first

    bf16x8 af[4], bfr[4];
    #pragma unroll
    for (int mi = 0; mi < 4; ++mi) af[mi] = *(const bf16x8*)&As[cur][offA[mi]];
    #pragma unroll
    for (int ni = 0; ni < 4; ++ni) bfr[ni] = *(const bf16x8*)&Bs[cur][offB[ni]];
    #pragma unroll
    for (int mi = 0; mi < 4; ++mi)
      #pragma unroll
      for (int ni = 0; ni < 4; ++ni)
        acc[mi][ni] = __builtin_amdgcn_mfma_f32_16x16x32_bf16(
            af[mi], bfr[ni], acc[mi][ni], 0, 0, 0);

    asm volatile("s_waitcnt vmcnt(0)" ::: "memory");
    __syncthreads();
    cur ^= 1;
  }

  #pragma unroll
  for (int mi = 0; mi < 4; ++mi) {
    int rowb = bm + wr * 64 + mi * 16 + l4 * 4;
    #pragma unroll
    for (int ni = 0; ni < 4; ++ni) {
      int col = bn + wc * 64 + ni * 16 + l15;
      float bv = bias ? bias[col] : 0.f;
      #pragma unroll
      for (int r = 0; r < 4; ++r) {
        int row = rowb + r;
        if (row < M) {
          float v = acc[mi][ni][r] + bv;
          if constexpr (sizeof(OutT) == 2)
            Cout[(size_t)row * Nn + col] = (OutT)f2bf(v);
          else
            Cout[(size_t)row * Nn + col] = (OutT)v;
        }
      }
    }
  }
}

// ---------------------------------------------------------------------------
// Weight prep (once per launch)
// ---------------------------------------------------------------------------
__global__ void prep_wgcn_kernel(const float* __restrict__ W, unsigned short* __restrict__ Wt) {
  int i = blockIdx.x * blockDim.x + threadIdx.x;  // l*C*C + n*C + k
  if (i < L_ * C_ * C_) {
    int l = i / (C_ * C_);
    int rem = i - l * C_ * C_;
    int nn = rem >> 8, k = rem & 255;
    Wt[i] = f2bf(W[l * C_ * C_ + k * C_ + nn]);
  }
}
__global__ void prep_cast_kernel(const float* __restrict__ W, unsigned short* __restrict__ Wt, int n) {
  int i = blockIdx.x * blockDim.x + threadIdx.x;
  if (i < n) Wt[i] = f2bf(W[i]);
}
__global__ void quant_kernel(const float* __restrict__ in, unsigned short* __restrict__ out, int n4) {
  int i = blockIdx.x * blockDim.x + threadIdx.x;
  if (i < n4) {
    float4 v = ((const float4*)in)[i];
    ushort4 q;
    q.x = f2bf(v.x); q.y = f2bf(v.y); q.z = f2bf(v.z); q.w = f2bf(v.w);
    *(ushort4*)&out[i * 4] = q;
  }
}

// ---------------------------------------------------------------------------
// Per-snapshot graph preprocessing (fp32)
// ---------------------------------------------------------------------------
__global__ void init_deg_kernel(float* __restrict__ deg, int* __restrict__ cnt,
                                int* __restrict__ fill, int n) {
  int i = blockIdx.x * blockDim.x + threadIdx.x;
  if (i < n) { deg[i] = 1.0f; cnt[i] = 0; fill[i] = 0; }
}
__global__ void deg_count_kernel(const int* __restrict__ col, const float* __restrict__ ew,
                                 float* __restrict__ deg, int* __restrict__ cnt, int E) {
  int e = blockIdx.x * blockDim.x + threadIdx.x;
  if (e < E) {
    int c = col[e];
    atomicAdd(&deg[c], ew[e]);
    atomicAdd(&cnt[c], 1);
  }
}
__global__ void dinv_kernel(const float* __restrict__ deg, float* __restrict__ dinv, int n) {
  int i = blockIdx.x * blockDim.x + threadIdx.x;
  if (i < n) {
    float d = deg[i];
    dinv[i] = (d > 0.f) ? rsqrtf(fmaxf(d, 1e-12f)) : 0.f;
  }
}
// 1024-thread block, wave-shuffle scan (4 barriers per 1024-chunk)
__global__ void scan_kernel(const int* __restrict__ cnt, int* __restrict__ rowptr, int n) {
  const int tid = threadIdx.x;
  const int lane = tid & 63, wv = tid >> 6;   // 16 waves
  __shared__ int wsum[16];
  __shared__ int carry_s;
  if (tid == 0) carry_s = 0;
  __syncthreads();
  for (int base = 0; base < n; base += 1024) {
    int i = base + tid;
    int v = (i < n) ? cnt[i] : 0;
    int acc = v;
    #pragma unroll
    for (int off = 1; off < 64; off <<= 1) {
      int t = __shfl_up(acc, off);
      if (lane >= off) acc += t;
    }
    if (lane == 63) wsum[wv] = acc;
    __syncthreads();
    if (wv == 0 && lane < 16) {
      int wvv = wsum[lane];
      int a = wvv;
      #pragma unroll
      for (int off = 1; off < 16; off <<= 1) {
        int t = __shfl_up(a, off);
        if (lane >= off) a += t;
      }
      wsum[lane] = a - wvv;   // exclusive prefix of wave sums
    }
    __syncthreads();
    int carry = carry_s;
    if (i < n) rowptr[i] = carry + wsum[wv] + acc - v;
    __syncthreads();
    if (tid == 1023) carry_s = carry + wsum[15] + acc;  // + total of this chunk
    __syncthreads();
  }
  if (tid == 0) rowptr[n] = carry_s;
}
__global__ void csr_fill_kernel(const int* __restrict__ row, const int* __restrict__ col,
                                const float* __restrict__ ew, const float* __restrict__ dinv,
                                const int* __restrict__ rowptr, int* __restrict__ fill,
                                int* __restrict__ src_sorted, float* __restrict__ norm_sorted, int E) {
  int e = blockIdx.x * blockDim.x + threadIdx.x;
  if (e < E) {
    int c = col[e];
    int r = row[e];
    int pos = rowptr[c] + atomicAdd(&fill[c], 1);
    src_sorted[pos] = r;
    norm_sorted[pos] = dinv[r] * ew[e] * dinv[c];
  }
}

// ---------------------------------------------------------------------------
// Fused: out[n,:] = bf16(ReLU(LN( self + sum norm*hW[src,:] + b_gcn )))
// ---------------------------------------------------------------------------
__global__ __launch_bounds__(256) void spmm_ln_relu_kernel(
    const unsigned short* __restrict__ hW, const int* __restrict__ rowptr,
    const int* __restrict__ src, const float* __restrict__ normv,
    const float* __restrict__ dinv, const float* __restrict__ bgcn,
    const float* __restrict__ lnsc, const float* __restrict__ lnbi,
    unsigned short* __restrict__ out)
{
  __shared__ int s_src[256];
  __shared__ float s_nrm[256];
  int n = blockIdx.x;
  int c = threadIdx.x;
  float dv = dinv[n];
  float acc = dv * dv * bf2f(hW[(size_t)n * C_ + c]);  // self loop (ew=1)
  int e0 = rowptr[n], e1 = rowptr[n + 1];
  for (int base = e0; base < e1; base += 256) {
    int ee = base + c;
    if (ee < e1) { s_src[c] = src[ee]; s_nrm[c] = normv[ee]; }
    __syncthreads();
    int cnt = min(256, e1 - base);
    for (int j = 0; j < cnt; ++j)
      acc = fmaf(s_nrm[j], bf2f(hW[(size_t)s_src[j] * C_ + c]), acc);
    __syncthreads();
  }
  acc += bgcn[c];

  float s1 = acc, s2 = acc * acc;
  #pragma unroll
  for (int off = 32; off > 0; off >>= 1) {
    s1 += __shfl_down(s1, off);
    s2 += __shfl_down(s2, off);
  }
  __shared__ float r1[4], r2[4];
  int wid = threadIdx.x >> 6, lane = threadIdx.x & 63;
  if (lane == 0) { r1[wid] = s1; r2[wid] = s2; }
  __syncthreads();
  float t1 = r1[0] + r1[1] + r1[2] + r1[3];
  float t2 = r2[0] + r2[1] + r2[2] + r2[3];
  float mu = t1 * (1.0f / C_);
  float var = t2 * (1.0f / C_) - mu * mu;
  float inv = rsqrtf(var + EPS_);
  float v = (acc - mu) * inv * lnsc[c] + lnbi[c];
  out[(size_t)n * C_ + c] = f2bf(fmaxf(v, 0.f));
}

// ---------------------------------------------------------------------------
// GRU pointwise (bf16 gi/gh): h = (1-z)*n + z*h ; writes fp32 h + bf16 hq
// ---------------------------------------------------------------------------
__global__ void gru_pointwise_kernel(const unsigned short* __restrict__ gi,
                                     const unsigned short* __restrict__ gh,
                                     float* __restrict__ h, unsigned short* __restrict__ hq,
                                     int rows) {
  int idx = blockIdx.x * blockDim.x + threadIdx.x;
  if (idx >= rows * 64) return;
  int i = idx >> 6, c4 = (idx & 63) << 2;
  const unsigned short* gir = gi + (size_t)i * 768;
  const unsigned short* ghr = gh + (size_t)i * 768;
  ushort4 ir = *(const ushort4*)&gir[c4];
  ushort4 iz = *(const ushort4*)&gir[256 + c4];
  ushort4 in_ = *(const ushort4*)&gir[512 + c4];
  ushort4 hr = *(const ushort4*)&ghr[c4];
  ushort4 hz = *(const ushort4*)&ghr[256 + c4];
  ushort4 hn = *(const ushort4*)&ghr[512 + c4];
  float4 hp = *(const float4*)&h[(size_t)i * 256 + c4];
  float4 ho;
  ushort4 hqo;
  const unsigned short* pir = (const unsigned short*)&ir;
  const unsigned short* piz = (const unsigned short*)&iz;
  const unsigned short* pin = (const unsigned short*)&in_;
  const unsigned short* phr = (const unsigned short*)&hr;
  const unsigned short* phz = (const unsigned short*)&hz;
  const unsigned short* phn = (const unsigned short*)&hn;
  const float* php = (const float*)&hp;
  float* pho = (float*)&ho;
  unsigned short* phq = (unsigned short*)&hqo;
  #pragma unroll
  for (int j = 0; j < 4; ++j) {
    float r = 1.f / (1.f + expf(-(bf2f(pir[j]) + bf2f(phr[j]))));
    float z = 1.f / (1.f + expf(-(bf2f(piz[j]) + bf2f(phz[j]))));
    float nn = tanhf(bf2f(pin[j]) + r * bf2f(phn[j]));
    float hv = (1.f - z) * nn + z * php[j];
    pho[j] = hv;
    phq[j] = f2bf(hv);
  }
  *(float4*)&h[(size_t)i * 256 + c4] = ho;
  *(ushort4*)&hq[(size_t)i * 256 + c4] = hqo;
}

// ---------------------------------------------------------------------------
extern "C" void kernel_launch(void* const* d_in, const int* in_sizes, int n_in,
                              void* d_out, int out_size, void* d_ws, size_t ws_size,
                              hipStream_t stream) {
  const float* x        = (const float*)d_in[0];
  const int*   edge_idx = (const int*)d_in[1];
  const float* edge_w   = (const float*)d_in[2];
  const float* W_gcn    = (const float*)d_in[3];
  const float* b_gcn    = (const float*)d_in[4];
  const float* ln_scale = (const float*)d_in[5];
  const float* ln_bias  = (const float*)d_in[6];
  const float* w_ih     = (const float*)d_in[7];
  const float* w_hh     = (const float*)d_in[8];
  const float* b_ih     = (const float*)d_in[9];
  const float* b_hh     = (const float*)d_in[10];
  float* h_out = (float*)d_out;

  char* p = (char*)d_ws;
  auto carve = [&](size_t bytes) -> void* {
    void* r = (void*)p;
    p += (bytes + 255) & ~(size_t)255;
    return r;
  };
  float* deg         = (float*)carve(N_ * 4);
  float* dinv        = (float*)carve(N_ * 4);
  int*   cnt         = (int*)carve(N_ * 4);
  int*   fill        = (int*)carve(N_ * 4);
  int*   rowptr      = (int*)carve((N_ + 1) * 4);
  int*   src_sorted  = (int*)carve((size_t)E_ * 4);
  float* norm_sorted = (float*)carve((size_t)E_ * 4);
  unsigned short* wt_gcn = (unsigned short*)carve((size_t)L_ * C_ * C_ * 2);
  unsigned short* wih_bf = (unsigned short*)carve((size_t)768 * C_ * 2);
  unsigned short* whh_bf = (unsigned short*)carve((size_t)768 * C_ * 2);
  unsigned short* xq = (unsigned short*)carve((size_t)N_ * C_ * 2);
  unsigned short* hW = (unsigned short*)carve((size_t)N_ * C_ * 2);
  unsigned short* fA = (unsigned short*)carve((size_t)N_ * C_ * 2);
  unsigned short* hq = (unsigned short*)carve((size_t)N_ * C_ * 2);

  size_t fixed = (size_t)(p - (char*)d_ws);
  int NCH = 50000;
  while (NCH > 3125 && fixed + 2 * ((size_t)NCH * 768 * 2 + 256) > ws_size) NCH >>= 1;
  unsigned short* gi = (unsigned short*)carve((size_t)NCH * 768 * 2);
  unsigned short* gh = (unsigned short*)carve((size_t)NCH * 768 * 2);

  hipMemsetAsync(d_out, 0, (size_t)N_ * C_ * 4, stream);
  hipMemsetAsync(hq, 0, (size_t)N_ * C_ * 2, stream);

  const int TB = 256;
  const int gN = (N_ + TB - 1) / TB;
  const int gE = (E_ + TB - 1) / TB;

  prep_wgcn_kernel<<<(L_ * C_ * C_ + TB - 1) / TB, TB, 0, stream>>>(W_gcn, wt_gcn);
  prep_cast_kernel<<<(768 * C_ + TB - 1) / TB, TB, 0, stream>>>(w_ih, wih_bf, 768 * C_);
  prep_cast_kernel<<<(768 * C_ + TB - 1) / TB, TB, 0, stream>>>(w_hh, whh_bf, 768 * C_);

  for (int s = 0; s < S_; ++s) {
    const int* row = edge_idx + (size_t)s * 2 * E_;
    const int* col = row + E_;
    const float* ew = edge_w + (size_t)s * E_;

    quant_kernel<<<(N_ * C_ / 4 + TB - 1) / TB, TB, 0, stream>>>(
        x + (size_t)s * N_ * C_, xq, N_ * C_ / 4);

    init_deg_kernel<<<gN, TB, 0, stream>>>(deg, cnt, fill, N_);
    deg_count_kernel<<<gE, TB, 0, stream>>>(col, ew, deg, cnt, E_);
    dinv_kernel<<<gN, TB, 0, stream>>>(deg, dinv, N_);
    scan_kernel<<<1, 1024, 0, stream>>>(cnt, rowptr, N_);
    csr_fill_kernel<<<gE, TB, 0, stream>>>(row, col, ew, dinv, rowptr, fill,
                                           src_sorted, norm_sorted, E_);

    // GCN layers: xq -> fA -> xq -> fA
    const unsigned short* hin = xq;
    unsigned short* feat = fA;
    for (int l = 0; l < L_; ++l) {
      unsigned short* fout = (l == 1) ? xq : fA;
      dim3 grid((N_ + 127) / 128, C_ / 128);
      gemm_bf16_kernel<unsigned short><<<grid, 256, 0, stream>>>(
          hin, wt_gcn + (size_t)l * C_ * C_, nullptr, hW, N_, C_, C_);
      spmm_ln_relu_kernel<<<N_, 256, 0, stream>>>(hW, rowptr, src_sorted, norm_sorted,
                                                  dinv, b_gcn + l * C_,
                                                  ln_scale + l * C_, ln_bias + l * C_,
                                                  fout);
      hin = fout;
      feat = fout;
    }

    // GRU step
    for (int k = 0; k < N_ / NCH; ++k) {
      const unsigned short* xoff = feat + (size_t)k * NCH * C_;
      const unsigned short* hoff_q = hq + (size_t)k * NCH * C_;
      float* hoff = h_out + (size_t)k * NCH * C_;
      unsigned short* hqoff = hq + (size_t)k * NCH * C_;
      dim3 grid((NCH + 127) / 128, 768 / 128);
      gemm_bf16_kernel<unsigned short><<<grid, 256, 0, stream>>>(
          xoff, wih_bf, b_ih, gi, NCH, 768, C_);
      gemm_bf16_kernel<unsigned short><<<grid, 256, 0, stream>>>(
          hoff_q, whh_bf, b_hh, gh, NCH, 768, C_);
      gru_pointwise_kernel<<<((size_t)NCH * 64 + TB - 1) / TB, TB, 0, stream>>>(
          gi, gh, hoff, hqoff, NCH);
    }
  }
}

// Round 4
// 2786.510 us; speedup vs baseline: 2.3515x; 1.1298x over previous
//
#include <hip/hip_runtime.h>
#include <cmath>

#define S_ 4
#define N_ 50000
#define C_ 256
#define E_ 800000
#define L_ 3
#define EPS_ 1e-5f

typedef __attribute__((ext_vector_type(8))) short bf16x8;
typedef __attribute__((ext_vector_type(4))) float f32x4;

__device__ __forceinline__ float bf2f(unsigned short s) {
  return __uint_as_float(((unsigned)s) << 16);
}
__device__ __forceinline__ unsigned short f2bf(float f) {
  unsigned u = __float_as_uint(f);
  return (unsigned short)((u + 0x7fffu + ((u >> 16) & 1u)) >> 16);  // RNE
}

__device__ __forceinline__ void gload_lds16(const void* g, void* l) {
  __builtin_amdgcn_global_load_lds(
      (const __attribute__((address_space(1))) unsigned int*)g,
      (__attribute__((address_space(3))) unsigned int*)l, 16, 0, 0);
}

// ---------------------------------------------------------------------------
// bf16 MFMA GEMM: Cout[M,Nn] = A[M,K](bf16) * Bt[Nn,K]^T(bf16) (+bias[col])
// 128x128 tile, BK=32, 256 threads (4 waves 2x2), 2-phase double-buffered LDS.
// ---------------------------------------------------------------------------
template<typename OutT>
__global__ __launch_bounds__(256) void gemm_bf16_kernel(
    const unsigned short* __restrict__ A, const unsigned short* __restrict__ Bt,
    const float* __restrict__ bias, OutT* __restrict__ Cout,
    int M, int Nn, int K)
{
  __shared__ alignas(16) unsigned short As[2][128 * 32];
  __shared__ alignas(16) unsigned short Bs[2][128 * 32];
  const int tid = threadIdx.x;
  const int lane = tid & 63;
  const int wid = tid >> 6;
  const int wr = wid >> 1, wc = wid & 1;
  const int bm = blockIdx.x * 128, bn = blockIdx.y * 128;
  const int l15 = lane & 15, l4 = lane >> 4;

  f32x4 acc[4][4] = {};

  int offA[4], offB[4];
  #pragma unroll
  for (int mi = 0; mi < 4; ++mi) {
    int ra = wr * 64 + mi * 16 + l15;
    offA[mi] = ra * 32 + ((l4 ^ ((ra >> 1) & 3)) << 3);
    int rb = wc * 64 + mi * 16 + l15;
    offB[mi] = rb * 32 + ((l4 ^ ((rb >> 1) & 3)) << 3);
  }
  const int rs = tid >> 2;
  const int gs = tid & 3;

  auto stage = [&](int buf, int k0) {
    #pragma unroll
    for (int t2 = 0; t2 < 2; ++t2) {
      int r = rs + t2 * 64;
      int q = gs ^ ((r >> 1) & 3);
      int arow = bm + r; if (arow >= M) arow = M - 1;
      gload_lds16(&A[(size_t)arow * K + k0 + q * 8], &As[buf][(t2 * 256 + tid) * 8]);
      int brow = bn + r;
      gload_lds16(&Bt[(size_t)brow * K + k0 + q * 8], &Bs[buf][(t2 * 256 + tid) * 8]);
    }
  };

  const int nt = K >> 5;
  stage(0, 0);
  asm volatile("s_waitcnt vmcnt(0)" ::: "memory");
  __syncthreads();

  int cur = 0;
  for (int t = 0; t < nt; ++t) {
    if (t + 1 < nt) stage(cur ^ 1, (t + 1) * 32);

    bf16x8 af[4], bfr[4];
    #pragma unroll
    for (int mi = 0; mi < 4; ++mi) af[mi] = *(const bf16x8*)&As[cur][offA[mi]];
    #pragma unroll
    for (int ni = 0; ni < 4; ++ni) bfr[ni] = *(const bf16x8*)&Bs[cur][offB[ni]];
    #pragma unroll
    for (int mi = 0; mi < 4; ++mi)
      #pragma unroll
      for (int ni = 0; ni < 4; ++ni)
        acc[mi][ni] = __builtin_amdgcn_mfma_f32_16x16x32_bf16(
            af[mi], bfr[ni], acc[mi][ni], 0, 0, 0);

    asm volatile("s_waitcnt vmcnt(0)" ::: "memory");
    __syncthreads();
    cur ^= 1;
  }

  #pragma unroll
  for (int mi = 0; mi < 4; ++mi) {
    int rowb = bm + wr * 64 + mi * 16 + l4 * 4;
    #pragma unroll
    for (int ni = 0; ni < 4; ++ni) {
      int col = bn + wc * 64 + ni * 16 + l15;
      float bv = bias ? bias[col] : 0.f;
      #pragma unroll
      for (int r = 0; r < 4; ++r) {
        int row = rowb + r;
        if (row < M) {
          float v = acc[mi][ni][r] + bv;
          if constexpr (sizeof(OutT) == 2)
            Cout[(size_t)row * Nn + col] = (OutT)f2bf(v);
          else
            Cout[(size_t)row * Nn + col] = (OutT)v;
        }
      }
    }
  }
}

// ---------------------------------------------------------------------------
// Weight prep
// ---------------------------------------------------------------------------
__global__ void prep_wgcn_kernel(const float* __restrict__ W, unsigned short* __restrict__ Wt) {
  int i = blockIdx.x * blockDim.x + threadIdx.x;  // l*C*C + n*C + k
  if (i < L_ * C_ * C_) {
    int l = i / (C_ * C_);
    int rem = i - l * C_ * C_;
    int nn = rem >> 8, k = rem & 255;
    Wt[i] = f2bf(W[l * C_ * C_ + k * C_ + nn]);
  }
}
__global__ void prep_cast_kernel(const float* __restrict__ W, unsigned short* __restrict__ Wt, int n) {
  int i = blockIdx.x * blockDim.x + threadIdx.x;
  if (i < n) Wt[i] = f2bf(W[i]);
}
__global__ void quant_kernel(const float* __restrict__ in, unsigned short* __restrict__ out, int n4) {
  int i = blockIdx.x * blockDim.x + threadIdx.x;
  if (i < n4) {
    float4 v = ((const float4*)in)[i];
    ushort4 q;
    q.x = f2bf(v.x); q.y = f2bf(v.y); q.z = f2bf(v.z); q.w = f2bf(v.w);
    *(ushort4*)&out[i * 4] = q;
  }
}

// ---------------------------------------------------------------------------
// Batched (all snapshots) graph preprocessing
// ---------------------------------------------------------------------------
__global__ void init_deg_kernel(float* __restrict__ deg, int* __restrict__ cnt,
                                int* __restrict__ fill, int n) {
  int i = blockIdx.x * blockDim.x + threadIdx.x;
  if (i < n) { deg[i] = 1.0f; cnt[i] = 0; fill[i] = 0; }
}
// e in [0, 4E); edge_idx layout [S,2,E]
__global__ void deg_count_all_kernel(const int* __restrict__ edge_idx,
                                     const float* __restrict__ edge_w,
                                     float* __restrict__ deg, int* __restrict__ cnt) {
  int e = blockIdx.x * blockDim.x + threadIdx.x;
  if (e < S_ * E_) {
    int s = e / E_;
    int ee = e - s * E_;
    int c = edge_idx[(size_t)s * 2 * E_ + E_ + ee];
    atomicAdd(&deg[s * N_ + c], edge_w[(size_t)s * E_ + ee]);
    atomicAdd(&cnt[s * N_ + c], 1);
  }
}
__global__ void dinv_kernel(const float* __restrict__ deg, float* __restrict__ dinv, int n) {
  int i = blockIdx.x * blockDim.x + threadIdx.x;
  if (i < n) {
    float d = deg[i];
    dinv[i] = (d > 0.f) ? rsqrtf(fmaxf(d, 1e-12f)) : 0.f;
  }
}
// grid = S_ blocks of 1024; block b scans its snapshot's cnt -> rowptr
__global__ void scan4_kernel(const int* __restrict__ cnt, int* __restrict__ rowptr) {
  const int tid = threadIdx.x;
  const int lane = tid & 63, wv = tid >> 6;   // 16 waves
  const int s = blockIdx.x;
  const int* cs = cnt + s * N_;
  int* rp = rowptr + s * (N_ + 1);
  __shared__ int wsum[16];
  __shared__ int carry_s;
  if (tid == 0) carry_s = 0;
  __syncthreads();
  for (int base = 0; base < N_; base += 1024) {
    int i = base + tid;
    int v = (i < N_) ? cs[i] : 0;
    int acc = v;
    #pragma unroll
    for (int off = 1; off < 64; off <<= 1) {
      int t = __shfl_up(acc, off);
      if (lane >= off) acc += t;
    }
    if (lane == 63) wsum[wv] = acc;
    __syncthreads();
    if (wv == 0 && lane < 16) {
      int wvv = wsum[lane];
      int a = wvv;
      #pragma unroll
      for (int off = 1; off < 16; off <<= 1) {
        int t = __shfl_up(a, off);
        if (lane >= off) a += t;
      }
      wsum[lane] = a - wvv;
    }
    __syncthreads();
    int carry = carry_s;
    if (i < N_) rp[i] = carry + wsum[wv] + acc - v;
    __syncthreads();
    if (tid == 1023) carry_s = carry + wsum[15] + acc;
    __syncthreads();
  }
  if (tid == 0) rp[N_] = carry_s;
}
__global__ void csr_fill_all_kernel(const int* __restrict__ edge_idx,
                                    const float* __restrict__ edge_w,
                                    const float* __restrict__ dinv,
                                    const int* __restrict__ rowptr, int* __restrict__ fill,
                                    int* __restrict__ src_sorted, float* __restrict__ norm_sorted) {
  int e = blockIdx.x * blockDim.x + threadIdx.x;
  if (e < S_ * E_) {
    int s = e / E_;
    int ee = e - s * E_;
    int r = edge_idx[(size_t)s * 2 * E_ + ee];
    int c = edge_idx[(size_t)s * 2 * E_ + E_ + ee];
    float w = edge_w[(size_t)s * E_ + ee];
    int pos = rowptr[s * (N_ + 1) + c] + atomicAdd(&fill[s * N_ + c], 1);
    src_sorted[(size_t)s * E_ + pos] = r;
    norm_sorted[(size_t)s * E_ + pos] = dinv[s * N_ + r] * w * dinv[s * N_ + c];
  }
}

// ---------------------------------------------------------------------------
// Batched fused spmm+LN+ReLU over all 4 snapshots. blockIdx.x in [0, 4N).
// 8-way unrolled gather (8 outstanding 512B reads per block -> BW-bound).
// ---------------------------------------------------------------------------
__global__ __launch_bounds__(256) void spmm_ln_relu_kernel(
    const unsigned short* __restrict__ hW, const int* __restrict__ rowptr,
    const int* __restrict__ src, const float* __restrict__ normv,
    const float* __restrict__ dinv, const float* __restrict__ bgcn,
    const float* __restrict__ lnsc, const float* __restrict__ lnbi,
    unsigned short* __restrict__ out)
{
  __shared__ int s_src[256];
  __shared__ float s_nrm[256];
  const int bid = blockIdx.x;
  const int s = bid / N_;
  const int n = bid - s * N_;
  const int c = threadIdx.x;
  const unsigned short* hWs = hW + (size_t)s * N_ * C_;
  const int* rp = rowptr + s * (N_ + 1);
  const int* srcs = src + (size_t)s * E_;
  const float* nrms = normv + (size_t)s * E_;

  float dv = dinv[s * N_ + n];
  float a0 = dv * dv * bf2f(hWs[(size_t)n * C_ + c]);  // self loop (ew=1)
  float a1 = 0.f, a2 = 0.f, a3 = 0.f, a4 = 0.f, a5 = 0.f, a6 = 0.f, a7 = 0.f;
  int e0 = rp[n], e1 = rp[n + 1];
  for (int base = e0; base < e1; base += 256) {
    int ee = base + c;
    if (ee < e1) { s_src[c] = srcs[ee]; s_nrm[c] = nrms[ee]; }
    __syncthreads();
    int cnt = min(256, e1 - base);
    int j = 0;
    for (; j + 8 <= cnt; j += 8) {
      int r0 = s_src[j + 0], r1 = s_src[j + 1], r2 = s_src[j + 2], r3 = s_src[j + 3];
      int r4 = s_src[j + 4], r5 = s_src[j + 5], r6 = s_src[j + 6], r7 = s_src[j + 7];
      float v0 = bf2f(hWs[(size_t)r0 * C_ + c]);
      float v1 = bf2f(hWs[(size_t)r1 * C_ + c]);
      float v2 = bf2f(hWs[(size_t)r2 * C_ + c]);
      float v3 = bf2f(hWs[(size_t)r3 * C_ + c]);
      float v4 = bf2f(hWs[(size_t)r4 * C_ + c]);
      float v5 = bf2f(hWs[(size_t)r5 * C_ + c]);
      float v6 = bf2f(hWs[(size_t)r6 * C_ + c]);
      float v7 = bf2f(hWs[(size_t)r7 * C_ + c]);
      a0 = fmaf(s_nrm[j + 0], v0, a0);
      a1 = fmaf(s_nrm[j + 1], v1, a1);
      a2 = fmaf(s_nrm[j + 2], v2, a2);
      a3 = fmaf(s_nrm[j + 3], v3, a3);
      a4 = fmaf(s_nrm[j + 4], v4, a4);
      a5 = fmaf(s_nrm[j + 5], v5, a5);
      a6 = fmaf(s_nrm[j + 6], v6, a6);
      a7 = fmaf(s_nrm[j + 7], v7, a7);
    }
    for (; j < cnt; ++j)
      a0 = fmaf(s_nrm[j], bf2f(hWs[(size_t)s_src[j] * C_ + c]), a0);
    __syncthreads();
  }
  float acc = ((a0 + a1) + (a2 + a3)) + ((a4 + a5) + (a6 + a7));
  acc += bgcn[c];

  float s1 = acc, s2 = acc * acc;
  #pragma unroll
  for (int off = 32; off > 0; off >>= 1) {
    s1 += __shfl_down(s1, off);
    s2 += __shfl_down(s2, off);
  }
  __shared__ float r1[4], r2[4];
  int wid = threadIdx.x >> 6, lane = threadIdx.x & 63;
  if (lane == 0) { r1[wid] = s1; r2[wid] = s2; }
  __syncthreads();
  float t1 = r1[0] + r1[1] + r1[2] + r1[3];
  float t2 = r2[0] + r2[1] + r2[2] + r2[3];
  float mu = t1 * (1.0f / C_);
  float var = t2 * (1.0f / C_) - mu * mu;
  float inv = rsqrtf(var + EPS_);
  float v = (acc - mu) * inv * lnsc[c] + lnbi[c];
  out[(size_t)bid * C_ + c] = f2bf(fmaxf(v, 0.f));
}

// ---------------------------------------------------------------------------
// GRU pointwise (bf16 gi/gh): h = (1-z)*n + z*h ; writes fp32 h + bf16 hq
// ---------------------------------------------------------------------------
__global__ void gru_pointwise_kernel(const unsigned short* __restrict__ gi,
                                     const unsigned short* __restrict__ gh,
                                     float* __restrict__ h, unsigned short* __restrict__ hq,
                                     int rows) {
  int idx = blockIdx.x * blockDim.x + threadIdx.x;
  if (idx >= rows * 64) return;
  int i = idx >> 6, c4 = (idx & 63) << 2;
  const unsigned short* gir = gi + (size_t)i * 768;
  const unsigned short* ghr = gh + (size_t)i * 768;
  ushort4 ir = *(const ushort4*)&gir[c4];
  ushort4 iz = *(const ushort4*)&gir[256 + c4];
  ushort4 in_ = *(const ushort4*)&gir[512 + c4];
  ushort4 hr = *(const ushort4*)&ghr[c4];
  ushort4 hz = *(const ushort4*)&ghr[256 + c4];
  ushort4 hn = *(const ushort4*)&ghr[512 + c4];
  float4 hp = *(const float4*)&h[(size_t)i * 256 + c4];
  float4 ho;
  ushort4 hqo;
  const unsigned short* pir = (const unsigned short*)&ir;
  const unsigned short* piz = (const unsigned short*)&iz;
  const unsigned short* pin = (const unsigned short*)&in_;
  const unsigned short* phr = (const unsigned short*)&hr;
  const unsigned short* phz = (const unsigned short*)&hz;
  const unsigned short* phn = (const unsigned short*)&hn;
  const float* php = (const float*)&hp;
  float* pho = (float*)&ho;
  unsigned short* phq = (unsigned short*)&hqo;
  #pragma unroll
  for (int j = 0; j < 4; ++j) {
    float r = 1.f / (1.f + expf(-(bf2f(pir[j]) + bf2f(phr[j]))));
    float z = 1.f / (1.f + expf(-(bf2f(piz[j]) + bf2f(phz[j]))));
    float nn = tanhf(bf2f(pin[j]) + r * bf2f(phn[j]));
    float hv = (1.f - z) * nn + z * php[j];
    pho[j] = hv;
    phq[j] = f2bf(hv);
  }
  *(float4*)&h[(size_t)i * 256 + c4] = ho;
  *(ushort4*)&hq[(size_t)i * 256 + c4] = hqo;
}

// ---------------------------------------------------------------------------
extern "C" void kernel_launch(void* const* d_in, const int* in_sizes, int n_in,
                              void* d_out, int out_size, void* d_ws, size_t ws_size,
                              hipStream_t stream) {
  const float* x        = (const float*)d_in[0];
  const int*   edge_idx = (const int*)d_in[1];
  const float* edge_w   = (const float*)d_in[2];
  const float* W_gcn    = (const float*)d_in[3];
  const float* b_gcn    = (const float*)d_in[4];
  const float* ln_scale = (const float*)d_in[5];
  const float* ln_bias  = (const float*)d_in[6];
  const float* w_ih     = (const float*)d_in[7];
  const float* w_hh     = (const float*)d_in[8];
  const float* b_ih     = (const float*)d_in[9];
  const float* b_hh     = (const float*)d_in[10];
  float* h_out = (float*)d_out;

  char* p = (char*)d_ws;
  auto carve = [&](size_t bytes) -> void* {
    void* r = (void*)p;
    p += (bytes + 255) & ~(size_t)255;
    return r;
  };
  float* deg         = (float*)carve((size_t)S_ * N_ * 4);
  float* dinv        = (float*)carve((size_t)S_ * N_ * 4);
  int*   cnt         = (int*)carve((size_t)S_ * N_ * 4);
  int*   fill        = (int*)carve((size_t)S_ * N_ * 4);
  int*   rowptr      = (int*)carve((size_t)S_ * (N_ + 1) * 4);
  int*   src_sorted  = (int*)carve((size_t)S_ * E_ * 4);
  float* norm_sorted = (float*)carve((size_t)S_ * E_ * 4);
  unsigned short* wt_gcn = (unsigned short*)carve((size_t)L_ * C_ * C_ * 2);
  unsigned short* wih_bf = (unsigned short*)carve((size_t)768 * C_ * 2);
  unsigned short* whh_bf = (unsigned short*)carve((size_t)768 * C_ * 2);
  unsigned short* xq_all = (unsigned short*)carve((size_t)S_ * N_ * C_ * 2);
  unsigned short* hW_all = (unsigned short*)carve((size_t)S_ * N_ * C_ * 2);
  unsigned short* fA_all = (unsigned short*)carve((size_t)S_ * N_ * C_ * 2);
  unsigned short* hq     = (unsigned short*)carve((size_t)N_ * C_ * 2);

  size_t fixed = (size_t)(p - (char*)d_ws);
  size_t gi_big = (size_t)S_ * N_ * 768 * 2;
  size_t gi_small = (size_t)N_ * 768 * 2;
  size_t gh_sz = (size_t)N_ * 768 * 2;
  bool big_gi = (fixed + gi_big + gh_sz + 512 <= ws_size);
  unsigned short* gi_all = (unsigned short*)carve(big_gi ? gi_big : gi_small);
  unsigned short* gh     = (unsigned short*)carve(gh_sz);

  hipMemsetAsync(d_out, 0, (size_t)N_ * C_ * 4, stream);
  hipMemsetAsync(hq, 0, (size_t)N_ * C_ * 2, stream);

  const int TB = 256;

  prep_wgcn_kernel<<<(L_ * C_ * C_ + TB - 1) / TB, TB, 0, stream>>>(W_gcn, wt_gcn);
  prep_cast_kernel<<<(768 * C_ + TB - 1) / TB, TB, 0, stream>>>(w_ih, wih_bf, 768 * C_);
  prep_cast_kernel<<<(768 * C_ + TB - 1) / TB, TB, 0, stream>>>(w_hh, whh_bf, 768 * C_);

  // quantize all snapshots' x at once
  quant_kernel<<<((size_t)S_ * N_ * C_ / 4 + TB - 1) / TB, TB, 0, stream>>>(
      x, xq_all, S_ * N_ * C_ / 4);

  // batched preprocessing
  init_deg_kernel<<<(S_ * N_ + TB - 1) / TB, TB, 0, stream>>>(deg, cnt, fill, S_ * N_);
  deg_count_all_kernel<<<(S_ * E_ + TB - 1) / TB, TB, 0, stream>>>(edge_idx, edge_w, deg, cnt);
  dinv_kernel<<<(S_ * N_ + TB - 1) / TB, TB, 0, stream>>>(deg, dinv, S_ * N_);
  scan4_kernel<<<S_, 1024, 0, stream>>>(cnt, rowptr);
  csr_fill_all_kernel<<<(S_ * E_ + TB - 1) / TB, TB, 0, stream>>>(
      edge_idx, edge_w, dinv, rowptr, fill, src_sorted, norm_sorted);

  // GCN layers, all snapshots batched: xq_all -> fA_all -> xq_all -> fA_all
  const int M_all = S_ * N_;
  {
    const unsigned short* hin = xq_all;
    for (int l = 0; l < L_; ++l) {
      unsigned short* fout = (l == 1) ? xq_all : fA_all;
      dim3 grid((M_all + 127) / 128, C_ / 128);
      gemm_bf16_kernel<unsigned short><<<grid, 256, 0, stream>>>(
          hin, wt_gcn + (size_t)l * C_ * C_, nullptr, hW_all, M_all, C_, C_);
      spmm_ln_relu_kernel<<<M_all, 256, 0, stream>>>(
          hW_all, rowptr, src_sorted, norm_sorted, dinv, b_gcn + l * C_,
          ln_scale + l * C_, ln_bias + l * C_, fout);
      hin = fout;
    }
  }
  const unsigned short* feat_all = fA_all;

  // GRU input gates for all steps in one GEMM (if workspace allows)
  if (big_gi) {
    dim3 grid((M_all + 127) / 128, 768 / 128);
    gemm_bf16_kernel<unsigned short><<<grid, 256, 0, stream>>>(
        feat_all, wih_bf, b_ih, gi_all, M_all, 768, C_);
  }

  // GRU recurrence
  for (int s = 0; s < S_; ++s) {
    const unsigned short* gi_s;
    if (big_gi) {
      gi_s = gi_all + (size_t)s * N_ * 768;
    } else {
      dim3 grid((N_ + 127) / 128, 768 / 128);
      gemm_bf16_kernel<unsigned short><<<grid, 256, 0, stream>>>(
          feat_all + (size_t)s * N_ * C_, wih_bf, b_ih, gi_all, N_, 768, C_);
      gi_s = gi_all;
    }
    dim3 grid((N_ + 127) / 128, 768 / 128);
    gemm_bf16_kernel<unsigned short><<<grid, 256, 0, stream>>>(
        hq, whh_bf, b_hh, gh, N_, 768, C_);
    gru_pointwise_kernel<<<((size_t)N_ * 64 + TB - 1) / TB, TB, 0, stream>>>(
        gi_s, gh, h_out, hq, N_);
  }
}

// Round 5
// 2483.026 us; speedup vs baseline: 2.6389x; 1.1222x over previous
//
#include <hip/hip_runtime.h>
#include <cmath>

#define S_ 4
#define N_ 50000
#define C_ 256
#define E_ 800000
#define L_ 3
#define EPS_ 1e-5f

typedef __attribute__((ext_vector_type(8))) short bf16x8;
typedef __attribute__((ext_vector_type(4))) float f32x4;

__device__ __forceinline__ float bf2f(unsigned short s) {
  return __uint_as_float(((unsigned)s) << 16);
}
__device__ __forceinline__ unsigned short f2bf(float f) {
  unsigned u = __float_as_uint(f);
  return (unsigned short)((u + 0x7fffu + ((u >> 16) & 1u)) >> 16);  // RNE
}

__device__ __forceinline__ void gload_lds16(const void* g, void* l) {
  __builtin_amdgcn_global_load_lds(
      (const __attribute__((address_space(1))) unsigned int*)g,
      (__attribute__((address_space(3))) unsigned int*)l, 16, 0, 0);
}

// ---------------------------------------------------------------------------
// bf16 MFMA GEMM: Cout[M,Nn] = A[M,K](bf16) * Bt[Nn,K]^T(bf16) (+bias[col])
// 128x128 tile, BK=32, 256 threads (4 waves 2x2), 2-phase double-buffered LDS.
// ---------------------------------------------------------------------------
template<typename OutT>
__global__ __launch_bounds__(256) void gemm_bf16_kernel(
    const unsigned short* __restrict__ A, const unsigned short* __restrict__ Bt,
    const float* __restrict__ bias, OutT* __restrict__ Cout,
    int M, int Nn, int K)
{
  __shared__ alignas(16) unsigned short As[2][128 * 32];
  __shared__ alignas(16) unsigned short Bs[2][128 * 32];
  const int tid = threadIdx.x;
  const int lane = tid & 63;
  const int wid = tid >> 6;
  const int wr = wid >> 1, wc = wid & 1;
  const int bm = blockIdx.x * 128, bn = blockIdx.y * 128;
  const int l15 = lane & 15, l4 = lane >> 4;

  f32x4 acc[4][4] = {};

  int offA[4], offB[4];
  #pragma unroll
  for (int mi = 0; mi < 4; ++mi) {
    int ra = wr * 64 + mi * 16 + l15;
    offA[mi] = ra * 32 + ((l4 ^ ((ra >> 1) & 3)) << 3);
    int rb = wc * 64 + mi * 16 + l15;
    offB[mi] = rb * 32 + ((l4 ^ ((rb >> 1) & 3)) << 3);
  }
  const int rs = tid >> 2;
  const int gs = tid & 3;

  auto stage = [&](int buf, int k0) {
    #pragma unroll
    for (int t2 = 0; t2 < 2; ++t2) {
      int r = rs + t2 * 64;
      int q = gs ^ ((r >> 1) & 3);
      int arow = bm + r; if (arow >= M) arow = M - 1;
      gload_lds16(&A[(size_t)arow * K + k0 + q * 8], &As[buf][(t2 * 256 + tid) * 8]);
      int brow = bn + r;
      gload_lds16(&Bt[(size_t)brow * K + k0 + q * 8], &Bs[buf][(t2 * 256 + tid) * 8]);
    }
  };

  const int nt = K >> 5;
  stage(0, 0);
  asm volatile("s_waitcnt vmcnt(0)" ::: "memory");
  __syncthreads();

  int cur = 0;
  for (int t = 0; t < nt; ++t) {
    if (t + 1 < nt) stage(cur ^ 1, (t + 1) * 32);

    bf16x8 af[4], bfr[4];
    #pragma unroll
    for (int mi = 0; mi < 4; ++mi) af[mi] = *(const bf16x8*)&As[cur][offA[mi]];
    #pragma unroll
    for (int ni = 0; ni < 4; ++ni) bfr[ni] = *(const bf16x8*)&Bs[cur][offB[ni]];
    #pragma unroll
    for (int mi = 0; mi < 4; ++mi)
      #pragma unroll
      for (int ni = 0; ni < 4; ++ni)
        acc[mi][ni] = __builtin_amdgcn_mfma_f32_16x16x32_bf16(
            af[mi], bfr[ni], acc[mi][ni], 0, 0, 0);

    asm volatile("s_waitcnt vmcnt(0)" ::: "memory");
    __syncthreads();
    cur ^= 1;
  }

  #pragma unroll
  for (int mi = 0; mi < 4; ++mi) {
    int rowb = bm + wr * 64 + mi * 16 + l4 * 4;
    #pragma unroll
    for (int ni = 0; ni < 4; ++ni) {
      int col = bn + wc * 64 + ni * 16 + l15;
      float bv = bias ? bias[col] : 0.f;
      #pragma unroll
      for (int r = 0; r < 4; ++r) {
        int row = rowb + r;
        if (row < M) {
          float v = acc[mi][ni][r] + bv;
          if constexpr (sizeof(OutT) == 2)
            Cout[(size_t)row * Nn + col] = (OutT)f2bf(v);
          else
            Cout[(size_t)row * Nn + col] = (OutT)v;
        }
      }
    }
  }
}

// ---------------------------------------------------------------------------
// Weight prep
// ---------------------------------------------------------------------------
__global__ void prep_wgcn_kernel(const float* __restrict__ W, unsigned short* __restrict__ Wt) {
  int i = blockIdx.x * blockDim.x + threadIdx.x;  // l*C*C + n*C + k
  if (i < L_ * C_ * C_) {
    int l = i / (C_ * C_);
    int rem = i - l * C_ * C_;
    int nn = rem >> 8, k = rem & 255;
    Wt[i] = f2bf(W[l * C_ * C_ + k * C_ + nn]);
  }
}
__global__ void prep_cast_kernel(const float* __restrict__ W, unsigned short* __restrict__ Wt, int n) {
  int i = blockIdx.x * blockDim.x + threadIdx.x;
  if (i < n) Wt[i] = f2bf(W[i]);
}
__global__ void quant_kernel(const float* __restrict__ in, unsigned short* __restrict__ out, int n4) {
  int i = blockIdx.x * blockDim.x + threadIdx.x;
  if (i < n4) {
    float4 v = ((const float4*)in)[i];
    ushort4 q;
    q.x = f2bf(v.x); q.y = f2bf(v.y); q.z = f2bf(v.z); q.w = f2bf(v.w);
    *(ushort4*)&out[i * 4] = q;
  }
}

// ---------------------------------------------------------------------------
// Batched (all snapshots) graph preprocessing
// ---------------------------------------------------------------------------
__global__ void init_deg_kernel(float* __restrict__ deg, int* __restrict__ cnt,
                                int* __restrict__ fill, int n) {
  int i = blockIdx.x * blockDim.x + threadIdx.x;
  if (i < n) { deg[i] = 1.0f; cnt[i] = 0; fill[i] = 0; }
}
__global__ void deg_count_all_kernel(const int* __restrict__ edge_idx,
                                     const float* __restrict__ edge_w,
                                     float* __restrict__ deg, int* __restrict__ cnt) {
  int e = blockIdx.x * blockDim.x + threadIdx.x;
  if (e < S_ * E_) {
    int s = e / E_;
    int ee = e - s * E_;
    int c = edge_idx[(size_t)s * 2 * E_ + E_ + ee];
    atomicAdd(&deg[s * N_ + c], edge_w[(size_t)s * E_ + ee]);
    atomicAdd(&cnt[s * N_ + c], 1);
  }
}
__global__ void dinv_kernel(const float* __restrict__ deg, float* __restrict__ dinv, int n) {
  int i = blockIdx.x * blockDim.x + threadIdx.x;
  if (i < n) {
    float d = deg[i];
    dinv[i] = (d > 0.f) ? rsqrtf(fmaxf(d, 1e-12f)) : 0.f;
  }
}
__global__ void scan4_kernel(const int* __restrict__ cnt, int* __restrict__ rowptr) {
  const int tid = threadIdx.x;
  const int lane = tid & 63, wv = tid >> 6;   // 16 waves
  const int s = blockIdx.x;
  const int* cs = cnt + s * N_;
  int* rp = rowptr + s * (N_ + 1);
  __shared__ int wsum[16];
  __shared__ int carry_s;
  if (tid == 0) carry_s = 0;
  __syncthreads();
  for (int base = 0; base < N_; base += 1024) {
    int i = base + tid;
    int v = (i < N_) ? cs[i] : 0;
    int acc = v;
    #pragma unroll
    for (int off = 1; off < 64; off <<= 1) {
      int t = __shfl_up(acc, off);
      if (lane >= off) acc += t;
    }
    if (lane == 63) wsum[wv] = acc;
    __syncthreads();
    if (wv == 0 && lane < 16) {
      int wvv = wsum[lane];
      int a = wvv;
      #pragma unroll
      for (int off = 1; off < 16; off <<= 1) {
        int t = __shfl_up(a, off);
        if (lane >= off) a += t;
      }
      wsum[lane] = a - wvv;
    }
    __syncthreads();
    int carry = carry_s;
    if (i < N_) rp[i] = carry + wsum[wv] + acc - v;
    __syncthreads();
    if (tid == 1023) carry_s = carry + wsum[15] + acc;
    __syncthreads();
  }
  if (tid == 0) rp[N_] = carry_s;
}
__global__ void csr_fill_all_kernel(const int* __restrict__ edge_idx,
                                    const float* __restrict__ edge_w,
                                    const float* __restrict__ dinv,
                                    const int* __restrict__ rowptr, int* __restrict__ fill,
                                    int* __restrict__ src_sorted, float* __restrict__ norm_sorted) {
  int e = blockIdx.x * blockDim.x + threadIdx.x;
  if (e < S_ * E_) {
    int s = e / E_;
    int ee = e - s * E_;
    int r = edge_idx[(size_t)s * 2 * E_ + ee];
    int c = edge_idx[(size_t)s * 2 * E_ + E_ + ee];
    float w = edge_w[(size_t)s * E_ + ee];
    int pos = rowptr[s * (N_ + 1) + c] + atomicAdd(&fill[s * N_ + c], 1);
    src_sorted[(size_t)s * E_ + pos] = r;
    norm_sorted[(size_t)s * E_ + pos] = dinv[s * N_ + r] * w * dinv[s * N_ + c];
  }
}

// ---------------------------------------------------------------------------
// Per-snapshot fused spmm+LN+ReLU. Wave-per-edge gather: each lane loads
// ushort4 (8B) so one wave fetches a full 512B row; 4 waves x 4-deep unroll
// = 16 rows in flight per block. Cross-wave combine in LDS, then LN.
// ---------------------------------------------------------------------------
__global__ __launch_bounds__(256) void spmm_ln_relu_kernel(
    const unsigned short* __restrict__ hW, const int* __restrict__ rowptr,
    const int* __restrict__ src, const float* __restrict__ normv,
    const float* __restrict__ dinv, const float* __restrict__ bgcn,
    const float* __restrict__ lnsc, const float* __restrict__ lnbi,
    unsigned short* __restrict__ out)
{
  __shared__ int s_src[256];
  __shared__ float s_nrm[256];
  __shared__ float s_acc[4][256];
  const int n = blockIdx.x;
  const int tid = threadIdx.x;
  const int lane = tid & 63, wv = tid >> 6;
  const int c4 = lane << 2;            // channel base within wave

  float a0 = 0.f, a1 = 0.f, a2 = 0.f, a3 = 0.f;
  const int e0 = rowptr[n], e1 = rowptr[n + 1];
  for (int base = e0; base < e1; base += 256) {
    int cnt = min(256, e1 - base);
    if (tid < cnt) { s_src[tid] = src[base + tid]; s_nrm[tid] = normv[base + tid]; }
    __syncthreads();
    int j = wv;
    for (; j + 12 < cnt; j += 16) {
      int r0 = s_src[j], r1 = s_src[j + 4], r2 = s_src[j + 8], r3 = s_src[j + 12];
      float n0 = s_nrm[j], n1 = s_nrm[j + 4], n2 = s_nrm[j + 8], n3 = s_nrm[j + 12];
      ushort4 u0 = *(const ushort4*)&hW[((size_t)r0 << 8) + c4];
      ushort4 u1 = *(const ushort4*)&hW[((size_t)r1 << 8) + c4];
      ushort4 u2 = *(const ushort4*)&hW[((size_t)r2 << 8) + c4];
      ushort4 u3 = *(const ushort4*)&hW[((size_t)r3 << 8) + c4];
      a0 = fmaf(n0, bf2f(u0.x), a0); a1 = fmaf(n0, bf2f(u0.y), a1);
      a2 = fmaf(n0, bf2f(u0.z), a2); a3 = fmaf(n0, bf2f(u0.w), a3);
      a0 = fmaf(n1, bf2f(u1.x), a0); a1 = fmaf(n1, bf2f(u1.y), a1);
      a2 = fmaf(n1, bf2f(u1.z), a2); a3 = fmaf(n1, bf2f(u1.w), a3);
      a0 = fmaf(n2, bf2f(u2.x), a0); a1 = fmaf(n2, bf2f(u2.y), a1);
      a2 = fmaf(n2, bf2f(u2.z), a2); a3 = fmaf(n2, bf2f(u2.w), a3);
      a0 = fmaf(n3, bf2f(u3.x), a0); a1 = fmaf(n3, bf2f(u3.y), a1);
      a2 = fmaf(n3, bf2f(u3.z), a2); a3 = fmaf(n3, bf2f(u3.w), a3);
    }
    for (; j < cnt; j += 4) {
      int r0 = s_src[j];
      float n0 = s_nrm[j];
      ushort4 u0 = *(const ushort4*)&hW[((size_t)r0 << 8) + c4];
      a0 = fmaf(n0, bf2f(u0.x), a0); a1 = fmaf(n0, bf2f(u0.y), a1);
      a2 = fmaf(n0, bf2f(u0.z), a2); a3 = fmaf(n0, bf2f(u0.w), a3);
    }
    __syncthreads();
  }
  s_acc[wv][c4 + 0] = a0; s_acc[wv][c4 + 1] = a1;
  s_acc[wv][c4 + 2] = a2; s_acc[wv][c4 + 3] = a3;
  __syncthreads();

  const int c = tid;
  float acc = (s_acc[0][c] + s_acc[1][c]) + (s_acc[2][c] + s_acc[3][c]);
  float dv = dinv[n];
  acc = fmaf(dv * dv, bf2f(hW[((size_t)n << 8) + c]), acc);   // self loop
  acc += bgcn[c];

  float s1 = acc, s2 = acc * acc;
  #pragma unroll
  for (int off = 32; off > 0; off >>= 1) {
    s1 += __shfl_down(s1, off);
    s2 += __shfl_down(s2, off);
  }
  __shared__ float r1[4], r2[4];
  if (lane == 0) { r1[wv] = s1; r2[wv] = s2; }
  __syncthreads();
  float t1 = r1[0] + r1[1] + r1[2] + r1[3];
  float t2 = r2[0] + r2[1] + r2[2] + r2[3];
  float mu = t1 * (1.0f / C_);
  float var = t2 * (1.0f / C_) - mu * mu;
  float inv = rsqrtf(var + EPS_);
  float v = (acc - mu) * inv * lnsc[c] + lnbi[c];
  out[((size_t)n << 8) + c] = f2bf(fmaxf(v, 0.f));
}

// ---------------------------------------------------------------------------
// GRU pointwise. gh == nullptr => first step (h0 = 0, gh = b_hh broadcast).
// ---------------------------------------------------------------------------
__global__ void gru_pointwise_kernel(const unsigned short* __restrict__ gi,
                                     const unsigned short* __restrict__ gh,
                                     const float* __restrict__ b_hh,
                                     float* __restrict__ h, unsigned short* __restrict__ hq,
                                     int rows) {
  int idx = blockIdx.x * blockDim.x + threadIdx.x;
  if (idx >= rows * 64) return;
  int i = idx >> 6, c4 = (idx & 63) << 2;
  const unsigned short* gir = gi + (size_t)i * 768;
  ushort4 ir = *(const ushort4*)&gir[c4];
  ushort4 iz = *(const ushort4*)&gir[256 + c4];
  ushort4 in_ = *(const ushort4*)&gir[512 + c4];
  float hrv[4], hzv[4], hnv[4], hpv[4];
  if (gh) {
    const unsigned short* ghr = gh + (size_t)i * 768;
    ushort4 hr = *(const ushort4*)&ghr[c4];
    ushort4 hz = *(const ushort4*)&ghr[256 + c4];
    ushort4 hn = *(const ushort4*)&ghr[512 + c4];
    float4 hp = *(const float4*)&h[(size_t)i * 256 + c4];
    const unsigned short* phr = (const unsigned short*)&hr;
    const unsigned short* phz = (const unsigned short*)&hz;
    const unsigned short* phn = (const unsigned short*)&hn;
    const float* php = (const float*)&hp;
    #pragma unroll
    for (int j = 0; j < 4; ++j) {
      hrv[j] = bf2f(phr[j]); hzv[j] = bf2f(phz[j]); hnv[j] = bf2f(phn[j]);
      hpv[j] = php[j];
    }
  } else {
    #pragma unroll
    for (int j = 0; j < 4; ++j) {
      hrv[j] = b_hh[c4 + j]; hzv[j] = b_hh[256 + c4 + j]; hnv[j] = b_hh[512 + c4 + j];
      hpv[j] = 0.f;
    }
  }
  const unsigned short* pir = (const unsigned short*)&ir;
  const unsigned short* piz = (const unsigned short*)&iz;
  const unsigned short* pin = (const unsigned short*)&in_;
  float4 ho;
  ushort4 hqo;
  float* pho = (float*)&ho;
  unsigned short* phq = (unsigned short*)&hqo;
  #pragma unroll
  for (int j = 0; j < 4; ++j) {
    float r = 1.f / (1.f + expf(-(bf2f(pir[j]) + hrv[j])));
    float z = 1.f / (1.f + expf(-(bf2f(piz[j]) + hzv[j])));
    float nn = tanhf(bf2f(pin[j]) + r * hnv[j]);
    float hv = (1.f - z) * nn + z * hpv[j];
    pho[j] = hv;
    phq[j] = f2bf(hv);
  }
  *(float4*)&h[(size_t)i * 256 + c4] = ho;
  *(ushort4*)&hq[(size_t)i * 256 + c4] = hqo;
}

// ---------------------------------------------------------------------------
extern "C" void kernel_launch(void* const* d_in, const int* in_sizes, int n_in,
                              void* d_out, int out_size, void* d_ws, size_t ws_size,
                              hipStream_t stream) {
  const float* x        = (const float*)d_in[0];
  const int*   edge_idx = (const int*)d_in[1];
  const float* edge_w   = (const float*)d_in[2];
  const float* W_gcn    = (const float*)d_in[3];
  const float* b_gcn    = (const float*)d_in[4];
  const float* ln_scale = (const float*)d_in[5];
  const float* ln_bias  = (const float*)d_in[6];
  const float* w_ih     = (const float*)d_in[7];
  const float* w_hh     = (const float*)d_in[8];
  const float* b_ih     = (const float*)d_in[9];
  const float* b_hh     = (const float*)d_in[10];
  float* h_out = (float*)d_out;

  char* p = (char*)d_ws;
  auto carve = [&](size_t bytes) -> void* {
    void* r = (void*)p;
    p += (bytes + 255) & ~(size_t)255;
    return r;
  };
  float* deg         = (float*)carve((size_t)S_ * N_ * 4);
  float* dinv        = (float*)carve((size_t)S_ * N_ * 4);
  int*   cnt         = (int*)carve((size_t)S_ * N_ * 4);
  int*   fill        = (int*)carve((size_t)S_ * N_ * 4);
  int*   rowptr      = (int*)carve((size_t)S_ * (N_ + 1) * 4);
  int*   src_sorted  = (int*)carve((size_t)S_ * E_ * 4);
  float* norm_sorted = (float*)carve((size_t)S_ * E_ * 4);
  unsigned short* wt_gcn = (unsigned short*)carve((size_t)L_ * C_ * C_ * 2);
  unsigned short* wih_bf = (unsigned short*)carve((size_t)768 * C_ * 2);
  unsigned short* whh_bf = (unsigned short*)carve((size_t)768 * C_ * 2);
  unsigned short* xq_all = (unsigned short*)carve((size_t)S_ * N_ * C_ * 2);
  unsigned short* hW_all = (unsigned short*)carve((size_t)S_ * N_ * C_ * 2);
  unsigned short* fA_all = (unsigned short*)carve((size_t)S_ * N_ * C_ * 2);
  unsigned short* hq     = (unsigned short*)carve((size_t)N_ * C_ * 2);

  size_t fixed = (size_t)(p - (char*)d_ws);
  size_t gi_big = (size_t)S_ * N_ * 768 * 2;
  size_t gi_small = (size_t)N_ * 768 * 2;
  size_t gh_sz = (size_t)N_ * 768 * 2;
  bool big_gi = (fixed + gi_big + gh_sz + 512 <= ws_size);
  unsigned short* gi_all = (unsigned short*)carve(big_gi ? gi_big : gi_small);
  unsigned short* gh     = (unsigned short*)carve(gh_sz);

  const int TB = 256;

  prep_wgcn_kernel<<<(L_ * C_ * C_ + TB - 1) / TB, TB, 0, stream>>>(W_gcn, wt_gcn);
  prep_cast_kernel<<<(768 * C_ + TB - 1) / TB, TB, 0, stream>>>(w_ih, wih_bf, 768 * C_);
  prep_cast_kernel<<<(768 * C_ + TB - 1) / TB, TB, 0, stream>>>(w_hh, whh_bf, 768 * C_);

  quant_kernel<<<((size_t)S_ * N_ * C_ / 4 + TB - 1) / TB, TB, 0, stream>>>(
      x, xq_all, S_ * N_ * C_ / 4);

  init_deg_kernel<<<(S_ * N_ + TB - 1) / TB, TB, 0, stream>>>(deg, cnt, fill, S_ * N_);
  deg_count_all_kernel<<<(S_ * E_ + TB - 1) / TB, TB, 0, stream>>>(edge_idx, edge_w, deg, cnt);
  dinv_kernel<<<(S_ * N_ + TB - 1) / TB, TB, 0, stream>>>(deg, dinv, S_ * N_);
  scan4_kernel<<<S_, 1024, 0, stream>>>(cnt, rowptr);
  csr_fill_all_kernel<<<(S_ * E_ + TB - 1) / TB, TB, 0, stream>>>(
      edge_idx, edge_w, dinv, rowptr, fill, src_sorted, norm_sorted);

  // GCN layers: GEMM batched over snapshots; spmm per snapshot (L2 locality)
  const int M_all = S_ * N_;
  {
    const unsigned short* hin = xq_all;
    for (int l = 0; l < L_; ++l) {
      unsigned short* fout = (l == 1) ? xq_all : fA_all;
      dim3 grid((M_all + 127) / 128, C_ / 128);
      gemm_bf16_kernel<unsigned short><<<grid, 256, 0, stream>>>(
          hin, wt_gcn + (size_t)l * C_ * C_, nullptr, hW_all, M_all, C_, C_);
      for (int s = 0; s < S_; ++s) {
        spmm_ln_relu_kernel<<<N_, 256, 0, stream>>>(
            hW_all + (size_t)s * N_ * C_, rowptr + s * (N_ + 1),
            src_sorted + (size_t)s * E_, norm_sorted + (size_t)s * E_,
            dinv + s * N_, b_gcn + l * C_,
            ln_scale + l * C_, ln_bias + l * C_, fout + (size_t)s * N_ * C_);
      }
      hin = fout;
    }
  }
  const unsigned short* feat_all = fA_all;

  // GRU input gates for all steps in one GEMM (if workspace allows)
  if (big_gi) {
    dim3 grid((M_all + 127) / 128, 768 / 128);
    gemm_bf16_kernel<unsigned short><<<grid, 256, 0, stream>>>(
        feat_all, wih_bf, b_ih, gi_all, M_all, 768, C_);
  }

  // GRU recurrence; s=0 specialized (h0 = 0 => skip gh GEMM)
  for (int s = 0; s < S_; ++s) {
    const unsigned short* gi_s;
    if (big_gi) {
      gi_s = gi_all + (size_t)s * N_ * 768;
    } else {
      dim3 grid((N_ + 127) / 128, 768 / 128);
      gemm_bf16_kernel<unsigned short><<<grid, 256, 0, stream>>>(
          feat_all + (size_t)s * N_ * C_, wih_bf, b_ih, gi_all, N_, 768, C_);
      gi_s = gi_all;
    }
    if (s == 0) {
      gru_pointwise_kernel<<<((size_t)N_ * 64 + TB - 1) / TB, TB, 0, stream>>>(
          gi_s, nullptr, b_hh, h_out, hq, N_);
    } else {
      dim3 grid((N_ + 127) / 128, 768 / 128);
      gemm_bf16_kernel<unsigned short><<<grid, 256, 0, stream>>>(
          hq, whh_bf, b_hh, gh, N_, 768, C_);
      gru_pointwise_kernel<<<((size_t)N_ * 64 + TB - 1) / TB, TB, 0, stream>>>(
          gi_s, gh, nullptr, h_out, hq, N_);
    }
  }
}

// Round 6
// 2221.399 us; speedup vs baseline: 2.9497x; 1.1178x over previous
//
#include <hip/hip_runtime.h>
#include <cmath>

#define S_ 4
#define N_ 50000
#define C_ 256
#define E_ 800000
#define L_ 3
#define EPS_ 1e-5f
#define NCH_ ((N_ + 1023) / 1024)

typedef __attribute__((ext_vector_type(8))) short bf16x8;
typedef __attribute__((ext_vector_type(4))) float f32x4;

__device__ __forceinline__ float bf2f(unsigned short s) {
  return __uint_as_float(((unsigned)s) << 16);
}
__device__ __forceinline__ unsigned short f2bf(float f) {
  unsigned u = __float_as_uint(f);
  return (unsigned short)((u + 0x7fffu + ((u >> 16) & 1u)) >> 16);  // RNE
}

__device__ __forceinline__ void gload_lds16(const void* g, void* l) {
  __builtin_amdgcn_global_load_lds(
      (const __attribute__((address_space(1))) unsigned int*)g,
      (__attribute__((address_space(3))) unsigned int*)l, 16, 0, 0);
}

// ---------------------------------------------------------------------------
// bf16 MFMA GEMM: Cout[M,Nn] = A[M,K](bf16) * Bt[Nn,K]^T(bf16) (+bias[col])
// 128x128 tile, BK=32, 256 threads (4 waves 2x2), 2-phase double-buffered LDS.
// ---------------------------------------------------------------------------
template<typename OutT>
__global__ __launch_bounds__(256) void gemm_bf16_kernel(
    const unsigned short* __restrict__ A, const unsigned short* __restrict__ Bt,
    const float* __restrict__ bias, OutT* __restrict__ Cout,
    int M, int Nn, int K)
{
  __shared__ alignas(16) unsigned short As[2][128 * 32];
  __shared__ alignas(16) unsigned short Bs[2][128 * 32];
  const int tid = threadIdx.x;
  const int lane = tid & 63;
  const int wid = tid >> 6;
  const int wr = wid >> 1, wc = wid & 1;
  const int bm = blockIdx.x * 128, bn = blockIdx.y * 128;
  const int l15 = lane & 15, l4 = lane >> 4;

  f32x4 acc[4][4] = {};

  int offA[4], offB[4];
  #pragma unroll
  for (int mi = 0; mi < 4; ++mi) {
    int ra = wr * 64 + mi * 16 + l15;
    offA[mi] = ra * 32 + ((l4 ^ ((ra >> 1) & 3)) << 3);
    int rb = wc * 64 + mi * 16 + l15;
    offB[mi] = rb * 32 + ((l4 ^ ((rb >> 1) & 3)) << 3);
  }
  const int rs = tid >> 2;
  const int gs = tid & 3;

  auto stage = [&](int buf, int k0) {
    #pragma unroll
    for (int t2 = 0; t2 < 2; ++t2) {
      int r = rs + t2 * 64;
      int q = gs ^ ((r >> 1) & 3);
      int arow = bm + r; if (arow >= M) arow = M - 1;
      gload_lds16(&A[(size_t)arow * K + k0 + q * 8], &As[buf][(t2 * 256 + tid) * 8]);
      int brow = bn + r;
      gload_lds16(&Bt[(size_t)brow * K + k0 + q * 8], &Bs[buf][(t2 * 256 + tid) * 8]);
    }
  };

  const int nt = K >> 5;
  stage(0, 0);
  asm volatile("s_waitcnt vmcnt(0)" ::: "memory");
  __syncthreads();

  int cur = 0;
  for (int t = 0; t < nt; ++t) {
    if (t + 1 < nt) stage(cur ^ 1, (t + 1) * 32);

    bf16x8 af[4], bfr[4];
    #pragma unroll
    for (int mi = 0; mi < 4; ++mi) af[mi] = *(const bf16x8*)&As[cur][offA[mi]];
    #pragma unroll
    for (int ni = 0; ni < 4; ++ni) bfr[ni] = *(const bf16x8*)&Bs[cur][offB[ni]];
    #pragma unroll
    for (int mi = 0; mi < 4; ++mi)
      #pragma unroll
      for (int ni = 0; ni < 4; ++ni)
        acc[mi][ni] = __builtin_amdgcn_mfma_f32_16x16x32_bf16(
            af[mi], bfr[ni], acc[mi][ni], 0, 0, 0);

    asm volatile("s_waitcnt vmcnt(0)" ::: "memory");
    __syncthreads();
    cur ^= 1;
  }

  #pragma unroll
  for (int mi = 0; mi < 4; ++mi) {
    int rowb = bm + wr * 64 + mi * 16 + l4 * 4;
    #pragma unroll
    for (int ni = 0; ni < 4; ++ni) {
      int col = bn + wc * 64 + ni * 16 + l15;
      float bv = bias ? bias[col] : 0.f;
      #pragma unroll
      for (int r = 0; r < 4; ++r) {
        int row = rowb + r;
        if (row < M) {
          float v = acc[mi][ni][r] + bv;
          if constexpr (sizeof(OutT) == 2)
            Cout[(size_t)row * Nn + col] = (OutT)f2bf(v);
          else
            Cout[(size_t)row * Nn + col] = (OutT)v;
        }
      }
    }
  }
}

// ---------------------------------------------------------------------------
// Weight prep
// ---------------------------------------------------------------------------
__global__ void prep_wgcn_kernel(const float* __restrict__ W, unsigned short* __restrict__ Wt) {
  int i = blockIdx.x * blockDim.x + threadIdx.x;  // l*C*C + n*C + k
  if (i < L_ * C_ * C_) {
    int l = i / (C_ * C_);
    int rem = i - l * C_ * C_;
    int nn = rem >> 8, k = rem & 255;
    Wt[i] = f2bf(W[l * C_ * C_ + k * C_ + nn]);
  }
}
__global__ void prep_cast_kernel(const float* __restrict__ W, unsigned short* __restrict__ Wt, int n) {
  int i = blockIdx.x * blockDim.x + threadIdx.x;
  if (i < n) Wt[i] = f2bf(W[i]);
}
__global__ void quant_kernel(const float* __restrict__ in, unsigned short* __restrict__ out, int n4) {
  int i = blockIdx.x * blockDim.x + threadIdx.x;
  if (i < n4) {
    float4 v = ((const float4*)in)[i];
    ushort4 q;
    q.x = f2bf(v.x); q.y = f2bf(v.y); q.z = f2bf(v.z); q.w = f2bf(v.w);
    *(ushort4*)&out[i * 4] = q;
  }
}

// ---------------------------------------------------------------------------
// Graph preprocessing. deg+cnt packed in one u64: cnt in bits[40:64),
// fixed-point weighted degree (2^-20) in bits[0:40). Integer atomics =>
// bit-deterministic and one L2 atomic per edge instead of two.
// ---------------------------------------------------------------------------
__global__ void init_kernel(unsigned long long* __restrict__ deg64,
                            int* __restrict__ fill, int n) {
  int i = blockIdx.x * blockDim.x + threadIdx.x;
  if (i < n) { deg64[i] = (1ULL << 20); fill[i] = 0; }   // self-loop weight 1.0
}
__global__ void deg_count_all_kernel(const int* __restrict__ edge_idx,
                                     const float* __restrict__ edge_w,
                                     unsigned long long* __restrict__ deg64) {
  int e = blockIdx.x * blockDim.x + threadIdx.x;
  if (e < S_ * E_) {
    int s = e / E_;
    int ee = e - s * E_;
    int c = edge_idx[(size_t)s * 2 * E_ + E_ + ee];
    float w = edge_w[(size_t)s * E_ + ee];
    unsigned long long q = (unsigned long long)__float2uint_rn(w * 1048576.0f);
    atomicAdd(&deg64[s * N_ + c], q + (1ULL << 40));
  }
}
__global__ void dinv_kernel(const unsigned long long* __restrict__ deg64,
                            float* __restrict__ dinv, int n) {
  int i = blockIdx.x * blockDim.x + threadIdx.x;
  if (i < n) {
    float d = (float)(deg64[i] & ((1ULL << 40) - 1)) * (1.0f / 1048576.0f);
    dinv[i] = rsqrtf(fmaxf(d, 1e-12f));
  }
}
// scan stage A: per-1024-chunk counts
__global__ void chunk_sum_kernel(const unsigned long long* __restrict__ deg64,
                                 int* __restrict__ chunk_sum) {
  int b = blockIdx.x;
  int s = b / NCH_, ch = b - s * NCH_;
  const unsigned long long* dg = deg64 + (size_t)s * N_;
  int base = ch * 1024 + threadIdx.x * 4;
  int v = 0;
  #pragma unroll
  for (int j = 0; j < 4; ++j)
    if (base + j < N_) v += (int)(dg[base + j] >> 40);
  #pragma unroll
  for (int off = 32; off > 0; off >>= 1) v += __shfl_down(v, off);
  __shared__ int ws[4];
  int lane = threadIdx.x & 63, wv = threadIdx.x >> 6;
  if (lane == 0) ws[wv] = v;
  __syncthreads();
  if (threadIdx.x == 0) chunk_sum[s * NCH_ + ch] = ws[0] + ws[1] + ws[2] + ws[3];
}
// scan stage B: exclusive scan of chunk sums (49 per snapshot; 4 threads)
__global__ void scan_chunks_kernel(int* __restrict__ chunk_sum, int* __restrict__ rowptr) {
  int s = threadIdx.x;
  if (s < S_) {
    int tot = 0;
    for (int ch = 0; ch < NCH_; ++ch) {
      int t = chunk_sum[s * NCH_ + ch];
      chunk_sum[s * NCH_ + ch] = tot;
      tot += t;
    }
    rowptr[s * (N_ + 1) + N_] = tot;
  }
}
// scan stage C: finalize rowptr (exclusive) within each chunk
__global__ void scan_final_kernel(const unsigned long long* __restrict__ deg64,
                                  const int* __restrict__ chunk_sum,
                                  int* __restrict__ rowptr) {
  int b = blockIdx.x;
  int s = b / NCH_, ch = b - s * NCH_;
  const unsigned long long* dg = deg64 + (size_t)s * N_;
  int t = threadIdx.x;
  int i0 = ch * 1024 + t * 4;
  int c0 = 0, c1 = 0, c2 = 0, c3 = 0;
  if (i0 + 0 < N_) c0 = (int)(dg[i0 + 0] >> 40);
  if (i0 + 1 < N_) c1 = (int)(dg[i0 + 1] >> 40);
  if (i0 + 2 < N_) c2 = (int)(dg[i0 + 2] >> 40);
  if (i0 + 3 < N_) c3 = (int)(dg[i0 + 3] >> 40);
  int tsum = c0 + c1 + c2 + c3;
  int lane = t & 63, wv = t >> 6;
  int inc = tsum;
  #pragma unroll
  for (int off = 1; off < 64; off <<= 1) {
    int u = __shfl_up(inc, off);
    if (lane >= off) inc += u;
  }
  __shared__ int ws[4];
  if (lane == 63) ws[wv] = inc;
  __syncthreads();
  int woff = 0;
  for (int k = 0; k < 4; ++k) if (k < wv) woff += ws[k];
  int off0 = chunk_sum[s * NCH_ + ch] + woff + inc - tsum;
  int* rp = rowptr + (size_t)s * (N_ + 1);
  if (i0 + 0 < N_) rp[i0 + 0] = off0;
  if (i0 + 1 < N_) rp[i0 + 1] = off0 + c0;
  if (i0 + 2 < N_) rp[i0 + 2] = off0 + c0 + c1;
  if (i0 + 3 < N_) rp[i0 + 3] = off0 + c0 + c1 + c2;
}
__global__ void csr_fill_all_kernel(const int* __restrict__ edge_idx,
                                    const float* __restrict__ edge_w,
                                    const float* __restrict__ dinv,
                                    const int* __restrict__ rowptr, int* __restrict__ fill,
                                    int2* __restrict__ src_norm) {
  int e = blockIdx.x * blockDim.x + threadIdx.x;
  if (e < S_ * E_) {
    int s = e / E_;
    int ee = e - s * E_;
    int r = edge_idx[(size_t)s * 2 * E_ + ee];
    int c = edge_idx[(size_t)s * 2 * E_ + E_ + ee];
    float w = edge_w[(size_t)s * E_ + ee];
    int pos = rowptr[s * (N_ + 1) + c] + atomicAdd(&fill[s * N_ + c], 1);
    float nrm = dinv[s * N_ + r] * w * dinv[s * N_ + c];
    int2 pk; pk.x = r; pk.y = __float_as_int(nrm);
    src_norm[(size_t)s * E_ + pos] = pk;
  }
}

// ---------------------------------------------------------------------------
// Per-snapshot fused spmm+LN+ReLU, wave-per-edge gather (ushort4/lane).
// ---------------------------------------------------------------------------
__global__ __launch_bounds__(256) void spmm_ln_relu_kernel(
    const unsigned short* __restrict__ hW, const int* __restrict__ rowptr,
    const int2* __restrict__ src_norm,
    const float* __restrict__ dinv, const float* __restrict__ bgcn,
    const float* __restrict__ lnsc, const float* __restrict__ lnbi,
    unsigned short* __restrict__ out)
{
  __shared__ int s_src[256];
  __shared__ float s_nrm[256];
  __shared__ float s_acc[4][256];
  const int n = blockIdx.x;
  const int tid = threadIdx.x;
  const int lane = tid & 63, wv = tid >> 6;
  const int c4 = lane << 2;

  float a0 = 0.f, a1 = 0.f, a2 = 0.f, a3 = 0.f;
  const int e0 = rowptr[n], e1 = rowptr[n + 1];
  for (int base = e0; base < e1; base += 256) {
    int cnt = min(256, e1 - base);
    if (tid < cnt) {
      int2 pk = src_norm[base + tid];
      s_src[tid] = pk.x;
      s_nrm[tid] = __int_as_float(pk.y);
    }
    __syncthreads();
    int j = wv;
    for (; j + 12 < cnt; j += 16) {
      int r0 = s_src[j], r1 = s_src[j + 4], r2 = s_src[j + 8], r3 = s_src[j + 12];
      float n0 = s_nrm[j], n1 = s_nrm[j + 4], n2 = s_nrm[j + 8], n3 = s_nrm[j + 12];
      ushort4 u0 = *(const ushort4*)&hW[((size_t)r0 << 8) + c4];
      ushort4 u1 = *(const ushort4*)&hW[((size_t)r1 << 8) + c4];
      ushort4 u2 = *(const ushort4*)&hW[((size_t)r2 << 8) + c4];
      ushort4 u3 = *(const ushort4*)&hW[((size_t)r3 << 8) + c4];
      a0 = fmaf(n0, bf2f(u0.x), a0); a1 = fmaf(n0, bf2f(u0.y), a1);
      a2 = fmaf(n0, bf2f(u0.z), a2); a3 = fmaf(n0, bf2f(u0.w), a3);
      a0 = fmaf(n1, bf2f(u1.x), a0); a1 = fmaf(n1, bf2f(u1.y), a1);
      a2 = fmaf(n1, bf2f(u1.z), a2); a3 = fmaf(n1, bf2f(u1.w), a3);
      a0 = fmaf(n2, bf2f(u2.x), a0); a1 = fmaf(n2, bf2f(u2.y), a1);
      a2 = fmaf(n2, bf2f(u2.z), a2); a3 = fmaf(n2, bf2f(u2.w), a3);
      a0 = fmaf(n3, bf2f(u3.x), a0); a1 = fmaf(n3, bf2f(u3.y), a1);
      a2 = fmaf(n3, bf2f(u3.z), a2); a3 = fmaf(n3, bf2f(u3.w), a3);
    }
    for (; j < cnt; j += 4) {
      int r0 = s_src[j];
      float n0 = s_nrm[j];
      ushort4 u0 = *(const ushort4*)&hW[((size_t)r0 << 8) + c4];
      a0 = fmaf(n0, bf2f(u0.x), a0); a1 = fmaf(n0, bf2f(u0.y), a1);
      a2 = fmaf(n0, bf2f(u0.z), a2); a3 = fmaf(n0, bf2f(u0.w), a3);
    }
    __syncthreads();
  }
  s_acc[wv][c4 + 0] = a0; s_acc[wv][c4 + 1] = a1;
  s_acc[wv][c4 + 2] = a2; s_acc[wv][c4 + 3] = a3;
  __syncthreads();

  const int c = tid;
  float acc = (s_acc[0][c] + s_acc[1][c]) + (s_acc[2][c] + s_acc[3][c]);
  float dv = dinv[n];
  acc = fmaf(dv * dv, bf2f(hW[((size_t)n << 8) + c]), acc);   // self loop
  acc += bgcn[c];

  float s1 = acc, s2 = acc * acc;
  #pragma unroll
  for (int off = 32; off > 0; off >>= 1) {
    s1 += __shfl_down(s1, off);
    s2 += __shfl_down(s2, off);
  }
  __shared__ float r1[4], r2[4];
  if (lane == 0) { r1[wv] = s1; r2[wv] = s2; }
  __syncthreads();
  float t1 = r1[0] + r1[1] + r1[2] + r1[3];
  float t2 = r2[0] + r2[1] + r2[2] + r2[3];
  float mu = t1 * (1.0f / C_);
  float var = t2 * (1.0f / C_) - mu * mu;
  float inv = rsqrtf(var + EPS_);
  float v = (acc - mu) * inv * lnsc[c] + lnbi[c];
  out[((size_t)n << 8) + c] = f2bf(fmaxf(v, 0.f));
}

// ---------------------------------------------------------------------------
// GRU pointwise. h carried in bf16 (hq). gh==null => s=0 (h0=0, gh=b_hh).
// hq_out==null on last step; hout!=null writes final fp32 hidden.
// ---------------------------------------------------------------------------
__global__ void gru_pointwise_kernel(const unsigned short* __restrict__ gi,
                                     const unsigned short* __restrict__ gh,
                                     const float* __restrict__ b_hh,
                                     const unsigned short* __restrict__ hq_in,
                                     unsigned short* __restrict__ hq_out,
                                     float* __restrict__ hout,
                                     int rows) {
  int idx = blockIdx.x * blockDim.x + threadIdx.x;
  if (idx >= rows * 64) return;
  int i = idx >> 6, c4 = (idx & 63) << 2;
  const unsigned short* gir = gi + (size_t)i * 768;
  ushort4 ir = *(const ushort4*)&gir[c4];
  ushort4 iz = *(const ushort4*)&gir[256 + c4];
  ushort4 in_ = *(const ushort4*)&gir[512 + c4];
  float hrv[4], hzv[4], hnv[4], hpv[4];
  if (gh) {
    const unsigned short* ghr = gh + (size_t)i * 768;
    ushort4 hr = *(const ushort4*)&ghr[c4];
    ushort4 hz = *(const ushort4*)&ghr[256 + c4];
    ushort4 hn = *(const ushort4*)&ghr[512 + c4];
    ushort4 hp = *(const ushort4*)&hq_in[(size_t)i * 256 + c4];
    const unsigned short* phr = (const unsigned short*)&hr;
    const unsigned short* phz = (const unsigned short*)&hz;
    const unsigned short* phn = (const unsigned short*)&hn;
    const unsigned short* php = (const unsigned short*)&hp;
    #pragma unroll
    for (int j = 0; j < 4; ++j) {
      hrv[j] = bf2f(phr[j]); hzv[j] = bf2f(phz[j]); hnv[j] = bf2f(phn[j]);
      hpv[j] = bf2f(php[j]);
    }
  } else {
    #pragma unroll
    for (int j = 0; j < 4; ++j) {
      hrv[j] = b_hh[c4 + j]; hzv[j] = b_hh[256 + c4 + j]; hnv[j] = b_hh[512 + c4 + j];
      hpv[j] = 0.f;
    }
  }
  const unsigned short* pir = (const unsigned short*)&ir;
  const unsigned short* piz = (const unsigned short*)&iz;
  const unsigned short* pin = (const unsigned short*)&in_;
  float hv[4];
  #pragma unroll
  for (int j = 0; j < 4; ++j) {
    float r = 1.f / (1.f + expf(-(bf2f(pir[j]) + hrv[j])));
    float z = 1.f / (1.f + expf(-(bf2f(piz[j]) + hzv[j])));
    float nn = tanhf(bf2f(pin[j]) + r * hnv[j]);
    hv[j] = (1.f - z) * nn + z * hpv[j];
  }
  if (hq_out) {
    ushort4 hqo;
    unsigned short* phq = (unsigned short*)&hqo;
    #pragma unroll
    for (int j = 0; j < 4; ++j) phq[j] = f2bf(hv[j]);
    *(ushort4*)&hq_out[(size_t)i * 256 + c4] = hqo;
  }
  if (hout) {
    float4 ho;
    float* pho = (float*)&ho;
    #pragma unroll
    for (int j = 0; j < 4; ++j) pho[j] = hv[j];
    *(float4*)&hout[(size_t)i * 256 + c4] = ho;
  }
}

// ---------------------------------------------------------------------------
extern "C" void kernel_launch(void* const* d_in, const int* in_sizes, int n_in,
                              void* d_out, int out_size, void* d_ws, size_t ws_size,
                              hipStream_t stream) {
  const float* x        = (const float*)d_in[0];
  const int*   edge_idx = (const int*)d_in[1];
  const float* edge_w   = (const float*)d_in[2];
  const float* W_gcn    = (const float*)d_in[3];
  const float* b_gcn    = (const float*)d_in[4];
  const float* ln_scale = (const float*)d_in[5];
  const float* ln_bias  = (const float*)d_in[6];
  const float* w_ih     = (const float*)d_in[7];
  const float* w_hh     = (const float*)d_in[8];
  const float* b_ih     = (const float*)d_in[9];
  const float* b_hh     = (const float*)d_in[10];
  float* h_out = (float*)d_out;

  char* p = (char*)d_ws;
  auto carve = [&](size_t bytes) -> void* {
    void* r = (void*)p;
    p += (bytes + 255) & ~(size_t)255;
    return r;
  };
  unsigned long long* deg64 = (unsigned long long*)carve((size_t)S_ * N_ * 8);
  float* dinv        = (float*)carve((size_t)S_ * N_ * 4);
  int*   fill        = (int*)carve((size_t)S_ * N_ * 4);
  int*   rowptr      = (int*)carve((size_t)S_ * (N_ + 1) * 4);
  int*   chunk_sum   = (int*)carve((size_t)S_ * NCH_ * 4);
  int2*  src_norm    = (int2*)carve((size_t)S_ * E_ * 8);
  unsigned short* wt_gcn = (unsigned short*)carve((size_t)L_ * C_ * C_ * 2);
  unsigned short* wih_bf = (unsigned short*)carve((size_t)768 * C_ * 2);
  unsigned short* whh_bf = (unsigned short*)carve((size_t)768 * C_ * 2);
  unsigned short* xq_all = (unsigned short*)carve((size_t)S_ * N_ * C_ * 2);
  unsigned short* hW_all = (unsigned short*)carve((size_t)S_ * N_ * C_ * 2);
  unsigned short* fA_all = (unsigned short*)carve((size_t)S_ * N_ * C_ * 2);
  unsigned short* hq     = (unsigned short*)carve((size_t)N_ * C_ * 2);

  size_t fixed = (size_t)(p - (char*)d_ws);
  size_t gi_big = (size_t)S_ * N_ * 768 * 2;
  size_t gi_small = (size_t)N_ * 768 * 2;
  size_t gh_sz = (size_t)N_ * 768 * 2;
  bool big_gi = (fixed + gi_big + gh_sz + 512 <= ws_size);
  unsigned short* gi_all = (unsigned short*)carve(big_gi ? gi_big : gi_small);
  unsigned short* gh     = (unsigned short*)carve(gh_sz);

  const int TB = 256;

  prep_wgcn_kernel<<<(L_ * C_ * C_ + TB - 1) / TB, TB, 0, stream>>>(W_gcn, wt_gcn);
  prep_cast_kernel<<<(768 * C_ + TB - 1) / TB, TB, 0, stream>>>(w_ih, wih_bf, 768 * C_);
  prep_cast_kernel<<<(768 * C_ + TB - 1) / TB, TB, 0, stream>>>(w_hh, whh_bf, 768 * C_);

  quant_kernel<<<((size_t)S_ * N_ * C_ / 4 + TB - 1) / TB, TB, 0, stream>>>(
      x, xq_all, S_ * N_ * C_ / 4);

  init_kernel<<<(S_ * N_ + TB - 1) / TB, TB, 0, stream>>>(deg64, fill, S_ * N_);
  deg_count_all_kernel<<<(S_ * E_ + TB - 1) / TB, TB, 0, stream>>>(edge_idx, edge_w, deg64);
  dinv_kernel<<<(S_ * N_ + TB - 1) / TB, TB, 0, stream>>>(deg64, dinv, S_ * N_);
  chunk_sum_kernel<<<S_ * NCH_, TB, 0, stream>>>(deg64, chunk_sum);
  scan_chunks_kernel<<<1, 64, 0, stream>>>(chunk_sum, rowptr);
  scan_final_kernel<<<S_ * NCH_, TB, 0, stream>>>(deg64, chunk_sum, rowptr);
  csr_fill_all_kernel<<<(S_ * E_ + TB - 1) / TB, TB, 0, stream>>>(
      edge_idx, edge_w, dinv, rowptr, fill, src_norm);

  // GCN layers: GEMM batched over snapshots; spmm per snapshot (L2 locality)
  const int M_all = S_ * N_;
  {
    const unsigned short* hin = xq_all;
    for (int l = 0; l < L_; ++l) {
      unsigned short* fout = (l == 1) ? xq_all : fA_all;
      dim3 grid((M_all + 127) / 128, C_ / 128);
      gemm_bf16_kernel<unsigned short><<<grid, 256, 0, stream>>>(
          hin, wt_gcn + (size_t)l * C_ * C_, nullptr, hW_all, M_all, C_, C_);
      for (int s = 0; s < S_; ++s) {
        spmm_ln_relu_kernel<<<N_, 256, 0, stream>>>(
            hW_all + (size_t)s * N_ * C_, rowptr + s * (N_ + 1),
            src_norm + (size_t)s * E_,
            dinv + s * N_, b_gcn + l * C_,
            ln_scale + l * C_, ln_bias + l * C_, fout + (size_t)s * N_ * C_);
      }
      hin = fout;
    }
  }
  const unsigned short* feat_all = fA_all;

  // GRU input gates for all steps in one GEMM (if workspace allows)
  if (big_gi) {
    dim3 grid((M_all + 127) / 128, 768 / 128);
    gemm_bf16_kernel<unsigned short><<<grid, 256, 0, stream>>>(
        feat_all, wih_bf, b_ih, gi_all, M_all, 768, C_);
  }

  // GRU recurrence; h carried in bf16 (hq); fp32 write only at last step
  for (int s = 0; s < S_; ++s) {
    const unsigned short* gi_s;
    if (big_gi) {
      gi_s = gi_all + (size_t)s * N_ * 768;
    } else {
      dim3 grid((N_ + 127) / 128, 768 / 128);
      gemm_bf16_kernel<unsigned short><<<grid, 256, 0, stream>>>(
          feat_all + (size_t)s * N_ * C_, wih_bf, b_ih, gi_all, N_, 768, C_);
      gi_s = gi_all;
    }
    if (s == 0) {
      gru_pointwise_kernel<<<((size_t)N_ * 64 + TB - 1) / TB, TB, 0, stream>>>(
          gi_s, nullptr, b_hh, nullptr, hq, nullptr, N_);
    } else {
      dim3 grid((N_ + 127) / 128, 768 / 128);
      gemm_bf16_kernel<unsigned short><<<grid, 256, 0, stream>>>(
          hq, whh_bf, b_hh, gh, N_, 768, C_);
      bool last = (s == S_ - 1);
      gru_pointwise_kernel<<<((size_t)N_ * 64 + TB - 1) / TB, TB, 0, stream>>>(
          gi_s, gh, nullptr, hq, last ? nullptr : hq, last ? h_out : nullptr, N_);
    }
  }
}

// Round 7
// 1987.602 us; speedup vs baseline: 3.2967x; 1.1176x over previous
//
#include <hip/hip_runtime.h>
#include <cmath>

#define S_ 4
#define N_ 50000
#define C_ 256
#define E_ 800000
#define L_ 3
#define EPS_ 1e-5f
#define NCH_ ((N_ + 1023) / 1024)

typedef __attribute__((ext_vector_type(8))) short bf16x8;
typedef __attribute__((ext_vector_type(4))) float f32x4;

__device__ __forceinline__ float bf2f(unsigned short s) {
  return __uint_as_float(((unsigned)s) << 16);
}
__device__ __forceinline__ unsigned short f2bf(float f) {
  unsigned u = __float_as_uint(f);
  return (unsigned short)((u + 0x7fffu + ((u >> 16) & 1u)) >> 16);  // RNE
}

__device__ __forceinline__ void gload_lds16(const void* g, void* l) {
  __builtin_amdgcn_global_load_lds(
      (const __attribute__((address_space(1))) unsigned int*)g,
      (__attribute__((address_space(3))) unsigned int*)l, 16, 0, 0);
}

// bijective XCD-aware panel swizzle: 1D id -> (bmi, bni), bni fastest within
// groups of 8 bm so same-bm blocks share an XCD L2 (blockIdx round-robins %8).
__device__ __forceinline__ void swz_block(int id, int nbx, int nby, int& bmi, int& bni) {
  const int NB8 = nby * 8;
  int fullb = (nbx >> 3) * NB8;
  if (id < fullb) {
    int g = id / NB8, pp = id - g * NB8;
    bmi = g * 8 + (pp & 7);
    bni = pp >> 3;
  } else {
    int rem = nbx & 7;
    int idp = id - fullb;
    bmi = (nbx & ~7) + idp % rem;
    bni = idp / rem;
  }
}

// ---------------------------------------------------------------------------
// bf16 MFMA GEMM: Cout[M,Nn] = A[M,K](bf16) * Bt[Nn,K]^T(bf16), bf16 out.
// 128x128 tile, BK=32, 256 threads, 2-phase dbuf LDS, swizzled 1D grid.
// ---------------------------------------------------------------------------
__global__ __launch_bounds__(256) void gemm_bf16_kernel(
    const unsigned short* __restrict__ A, const unsigned short* __restrict__ Bt,
    unsigned short* __restrict__ Cout, int M, int Nn, int K, int nby)
{
  __shared__ alignas(16) unsigned short As[2][128 * 32];
  __shared__ alignas(16) unsigned short Bs[2][128 * 32];
  const int tid = threadIdx.x;
  const int lane = tid & 63;
  const int wid = tid >> 6;
  const int wr = wid >> 1, wc = wid & 1;
  int bmi, bni;
  swz_block(blockIdx.x, gridDim.x / nby, nby, bmi, bni);
  const int bm = bmi * 128, bn = bni * 128;
  const int l15 = lane & 15, l4 = lane >> 4;

  f32x4 acc[4][4] = {};

  int offA[4], offB[4];
  #pragma unroll
  for (int mi = 0; mi < 4; ++mi) {
    int ra = wr * 64 + mi * 16 + l15;
    offA[mi] = ra * 32 + ((l4 ^ ((ra >> 1) & 3)) << 3);
    int rb = wc * 64 + mi * 16 + l15;
    offB[mi] = rb * 32 + ((l4 ^ ((rb >> 1) & 3)) << 3);
  }
  const int rs = tid >> 2;
  const int gs = tid & 3;

  auto stage = [&](int buf, int k0) {
    #pragma unroll
    for (int t2 = 0; t2 < 2; ++t2) {
      int r = rs + t2 * 64;
      int q = gs ^ ((r >> 1) & 3);
      int arow = bm + r; if (arow >= M) arow = M - 1;
      gload_lds16(&A[(size_t)arow * K + k0 + q * 8], &As[buf][(t2 * 256 + tid) * 8]);
      int brow = bn + r;
      gload_lds16(&Bt[(size_t)brow * K + k0 + q * 8], &Bs[buf][(t2 * 256 + tid) * 8]);
    }
  };

  const int nt = K >> 5;
  stage(0, 0);
  asm volatile("s_waitcnt vmcnt(0)" ::: "memory");
  __syncthreads();

  int cur = 0;
  for (int t = 0; t < nt; ++t) {
    if (t + 1 < nt) stage(cur ^ 1, (t + 1) * 32);

    bf16x8 af[4], bfr[4];
    #pragma unroll
    for (int mi = 0; mi < 4; ++mi) af[mi] = *(const bf16x8*)&As[cur][offA[mi]];
    #pragma unroll
    for (int ni = 0; ni < 4; ++ni) bfr[ni] = *(const bf16x8*)&Bs[cur][offB[ni]];
    #pragma unroll
    for (int mi = 0; mi < 4; ++mi)
      #pragma unroll
      for (int ni = 0; ni < 4; ++ni)
        acc[mi][ni] = __builtin_amdgcn_mfma_f32_16x16x32_bf16(
            af[mi], bfr[ni], acc[mi][ni], 0, 0, 0);

    asm volatile("s_waitcnt vmcnt(0)" ::: "memory");
    __syncthreads();
    cur ^= 1;
  }

  #pragma unroll
  for (int mi = 0; mi < 4; ++mi) {
    int rowb = bm + wr * 64 + mi * 16 + l4 * 4;
    #pragma unroll
    for (int ni = 0; ni < 4; ++ni) {
      int col = bn + wc * 64 + ni * 16 + l15;
      #pragma unroll
      for (int r = 0; r < 4; ++r) {
        int row = rowb + r;
        if (row < M) Cout[(size_t)row * Nn + col] = f2bf(acc[mi][ni][r]);
      }
    }
  }
}

// ---------------------------------------------------------------------------
// Fused GRU step: gates = feat*W_ih^T (+) hq*W_hh^T, epilogue does
// r/z/n + h update, writes bf16 hq_out (and fp32 hout on last step).
// Wp_* prepacked [8 chunks][96 rows = gate*32+dc][256 k].
// Block: 128 rows x (32 channels x 3 gates). 4 waves stacked vertically.
// ---------------------------------------------------------------------------
__global__ __launch_bounds__(256) void gru_fused_kernel(
    const unsigned short* __restrict__ feat,
    const unsigned short* __restrict__ hq_in,
    const unsigned short* __restrict__ Wp_ih,
    const unsigned short* __restrict__ Wp_hh,
    const float* __restrict__ b_ih, const float* __restrict__ b_hh,
    unsigned short* __restrict__ hq_out, float* __restrict__ hout,
    int first, int M)
{
  __shared__ alignas(16) unsigned short As[2][128 * 32];
  __shared__ alignas(16) unsigned short Bs[2][96 * 32];
  const int tid = threadIdx.x;
  const int lane = tid & 63;
  const int wv = tid >> 6;
  const int l15 = lane & 15, l4 = lane >> 4;

  int bmi, bni;
  swz_block(blockIdx.x, gridDim.x / 8, 8, bmi, bni);
  const int bm = bmi * 128;
  const int c0 = bni * 32;
  const int brow0 = bni * 96;

  f32x4 acc_i[2][6] = {};
  f32x4 acc_h[2][6] = {};

  int offA[2], offB[6];
  #pragma unroll
  for (int mi = 0; mi < 2; ++mi) {
    int ra = wv * 32 + mi * 16 + l15;
    offA[mi] = ra * 32 + ((l4 ^ ((ra >> 1) & 3)) << 3);
  }
  #pragma unroll
  for (int ni = 0; ni < 6; ++ni) {
    int rb = ni * 16 + l15;
    offB[ni] = rb * 32 + ((l4 ^ ((rb >> 1) & 3)) << 3);
  }

  const int nt = first ? 8 : 16;

  auto stage = [&](int buf, int t) {
    int k0 = (t & 7) * 32;
    const unsigned short* Ap = (t < 8) ? feat : hq_in;
    const unsigned short* Bp = (t < 8) ? Wp_ih : Wp_hh;
    #pragma unroll
    for (int t2 = 0; t2 < 2; ++t2) {
      int slot = t2 * 256 + tid;
      int r = slot >> 2;
      int q = (slot & 3) ^ ((r >> 1) & 3);
      int arow = bm + r; if (arow >= M) arow = M - 1;
      gload_lds16(&Ap[(size_t)arow * 256 + k0 + q * 8], &As[buf][slot * 8]);
    }
    {
      int slot = tid;
      int r = slot >> 2;
      int q = (slot & 3) ^ ((r >> 1) & 3);
      gload_lds16(&Bp[(size_t)(brow0 + r) * 256 + k0 + q * 8], &Bs[buf][slot * 8]);
    }
    if (tid < 128) {
      int slot = 256 + tid;
      int r = slot >> 2;
      int q = (slot & 3) ^ ((r >> 1) & 3);
      gload_lds16(&Bp[(size_t)(brow0 + r) * 256 + k0 + q * 8], &Bs[buf][slot * 8]);
    }
  };

  stage(0, 0);
  asm volatile("s_waitcnt vmcnt(0)" ::: "memory");
  __syncthreads();

  int cur = 0;
  for (int t = 0; t < nt; ++t) {
    if (t + 1 < nt) stage(cur ^ 1, t + 1);

    bf16x8 af[2], bfr[6];
    #pragma unroll
    for (int mi = 0; mi < 2; ++mi) af[mi] = *(const bf16x8*)&As[cur][offA[mi]];
    #pragma unroll
    for (int ni = 0; ni < 6; ++ni) bfr[ni] = *(const bf16x8*)&Bs[cur][offB[ni]];
    if (t < 8) {
      #pragma unroll
      for (int mi = 0; mi < 2; ++mi)
        #pragma unroll
        for (int ni = 0; ni < 6; ++ni)
          acc_i[mi][ni] = __builtin_amdgcn_mfma_f32_16x16x32_bf16(
              af[mi], bfr[ni], acc_i[mi][ni], 0, 0, 0);
    } else {
      #pragma unroll
      for (int mi = 0; mi < 2; ++mi)
        #pragma unroll
        for (int ni = 0; ni < 6; ++ni)
          acc_h[mi][ni] = __builtin_amdgcn_mfma_f32_16x16x32_bf16(
              af[mi], bfr[ni], acc_h[mi][ni], 0, 0, 0);
    }

    asm volatile("s_waitcnt vmcnt(0)" ::: "memory");
    __syncthreads();
    cur ^= 1;
  }

  #pragma unroll
  for (int cni = 0; cni < 2; ++cni) {
    int c = c0 + cni * 16 + l15;
    float bir = b_ih[c], biz = b_ih[256 + c], bin = b_ih[512 + c];
    float bhr = b_hh[c], bhz = b_hh[256 + c], bhn = b_hh[512 + c];
    #pragma unroll
    for (int mi = 0; mi < 2; ++mi) {
      int rowb = bm + wv * 32 + mi * 16 + l4 * 4;
      #pragma unroll
      for (int rr = 0; rr < 4; ++rr) {
        int row = rowb + rr;
        if (row < M) {
          float gir = acc_i[mi][0 + cni][rr] + bir;
          float ghr = acc_h[mi][0 + cni][rr] + bhr;
          float giz = acc_i[mi][2 + cni][rr] + biz;
          float ghz = acc_h[mi][2 + cni][rr] + bhz;
          float gin = acc_i[mi][4 + cni][rr] + bin;
          float ghn = acc_h[mi][4 + cni][rr] + bhn;
          float rg = 1.f / (1.f + expf(-(gir + ghr)));
          float zg = 1.f / (1.f + expf(-(giz + ghz)));
          float ng = tanhf(gin + rg * ghn);
          float hp = first ? 0.f : bf2f(hq_in[(size_t)row * 256 + c]);
          float hv = (1.f - zg) * ng + zg * hp;
          if (hq_out) hq_out[(size_t)row * 256 + c] = f2bf(hv);
          if (hout) hout[(size_t)row * 256 + c] = hv;
        }
      }
    }
  }
}

// ---------------------------------------------------------------------------
// Weight prep
// ---------------------------------------------------------------------------
__global__ void prep_wgcn_kernel(const float* __restrict__ W, unsigned short* __restrict__ Wt) {
  int i = blockIdx.x * blockDim.x + threadIdx.x;  // l*C*C + n*C + k
  if (i < L_ * C_ * C_) {
    int l = i / (C_ * C_);
    int rem = i - l * C_ * C_;
    int nn = rem >> 8, k = rem & 255;
    Wt[i] = f2bf(W[l * C_ * C_ + k * C_ + nn]);
  }
}
// pack [768,256] gate-major per 32-channel chunk: row chunk*96 + g*32 + dc
__global__ void prep_wp_kernel(const float* __restrict__ W, unsigned short* __restrict__ Wp) {
  int d = blockIdx.x * blockDim.x + threadIdx.x;
  if (d < 768 * 256) {
    int jrow = d >> 8, k = d & 255;
    int chunk = jrow / 96, j = jrow - chunk * 96;
    int g = j >> 5, dc = j & 31;
    int srow = g * 256 + chunk * 32 + dc;
    Wp[d] = f2bf(W[srow * 256 + k]);
  }
}
__global__ void quant_kernel(const float* __restrict__ in, unsigned short* __restrict__ out, int n4) {
  int i = blockIdx.x * blockDim.x + threadIdx.x;
  if (i < n4) {
    float4 v = ((const float4*)in)[i];
    ushort4 q;
    q.x = f2bf(v.x); q.y = f2bf(v.y); q.z = f2bf(v.z); q.w = f2bf(v.w);
    *(ushort4*)&out[i * 4] = q;
  }
}

// ---------------------------------------------------------------------------
// Graph preprocessing: deg+cnt packed u64 (cnt bits[40:64), fixed-point deg)
// ---------------------------------------------------------------------------
__global__ void init_kernel(unsigned long long* __restrict__ deg64,
                            int* __restrict__ fill, int n) {
  int i = blockIdx.x * blockDim.x + threadIdx.x;
  if (i < n) { deg64[i] = (1ULL << 20); fill[i] = 0; }
}
__global__ void deg_count_all_kernel(const int* __restrict__ edge_idx,
                                     const float* __restrict__ edge_w,
                                     unsigned long long* __restrict__ deg64) {
  int e = blockIdx.x * blockDim.x + threadIdx.x;
  if (e < S_ * E_) {
    int s = e / E_;
    int ee = e - s * E_;
    int c = edge_idx[(size_t)s * 2 * E_ + E_ + ee];
    float w = edge_w[(size_t)s * E_ + ee];
    unsigned long long q = (unsigned long long)__float2uint_rn(w * 1048576.0f);
    atomicAdd(&deg64[s * N_ + c], q + (1ULL << 40));
  }
}
__global__ void dinv_kernel(const unsigned long long* __restrict__ deg64,
                            float* __restrict__ dinv, int n) {
  int i = blockIdx.x * blockDim.x + threadIdx.x;
  if (i < n) {
    float d = (float)(deg64[i] & ((1ULL << 40) - 1)) * (1.0f / 1048576.0f);
    dinv[i] = rsqrtf(fmaxf(d, 1e-12f));
  }
}
__global__ void chunk_sum_kernel(const unsigned long long* __restrict__ deg64,
                                 int* __restrict__ chunk_sum) {
  int b = blockIdx.x;
  int s = b / NCH_, ch = b - s * NCH_;
  const unsigned long long* dg = deg64 + (size_t)s * N_;
  int base = ch * 1024 + threadIdx.x * 4;
  int v = 0;
  #pragma unroll
  for (int j = 0; j < 4; ++j)
    if (base + j < N_) v += (int)(dg[base + j] >> 40);
  #pragma unroll
  for (int off = 32; off > 0; off >>= 1) v += __shfl_down(v, off);
  __shared__ int ws[4];
  int lane = threadIdx.x & 63, wv = threadIdx.x >> 6;
  if (lane == 0) ws[wv] = v;
  __syncthreads();
  if (threadIdx.x == 0) chunk_sum[s * NCH_ + ch] = ws[0] + ws[1] + ws[2] + ws[3];
}
__global__ void scan_chunks_kernel(int* __restrict__ chunk_sum, int* __restrict__ rowptr) {
  int s = threadIdx.x;
  if (s < S_) {
    int tot = 0;
    for (int ch = 0; ch < NCH_; ++ch) {
      int t = chunk_sum[s * NCH_ + ch];
      chunk_sum[s * NCH_ + ch] = tot;
      tot += t;
    }
    rowptr[s * (N_ + 1) + N_] = tot;
  }
}
__global__ void scan_final_kernel(const unsigned long long* __restrict__ deg64,
                                  const int* __restrict__ chunk_sum,
                                  int* __restrict__ rowptr) {
  int b = blockIdx.x;
  int s = b / NCH_, ch = b - s * NCH_;
  const unsigned long long* dg = deg64 + (size_t)s * N_;
  int t = threadIdx.x;
  int i0 = ch * 1024 + t * 4;
  int c0 = 0, c1 = 0, c2 = 0, c3 = 0;
  if (i0 + 0 < N_) c0 = (int)(dg[i0 + 0] >> 40);
  if (i0 + 1 < N_) c1 = (int)(dg[i0 + 1] >> 40);
  if (i0 + 2 < N_) c2 = (int)(dg[i0 + 2] >> 40);
  if (i0 + 3 < N_) c3 = (int)(dg[i0 + 3] >> 40);
  int tsum = c0 + c1 + c2 + c3;
  int lane = t & 63, wv = t >> 6;
  int inc = tsum;
  #pragma unroll
  for (int off = 1; off < 64; off <<= 1) {
    int u = __shfl_up(inc, off);
    if (lane >= off) inc += u;
  }
  __shared__ int ws[4];
  if (lane == 63) ws[wv] = inc;
  __syncthreads();
  int woff = 0;
  for (int k = 0; k < 4; ++k) if (k < wv) woff += ws[k];
  int off0 = chunk_sum[s * NCH_ + ch] + woff + inc - tsum;
  int* rp = rowptr + (size_t)s * (N_ + 1);
  if (i0 + 0 < N_) rp[i0 + 0] = off0;
  if (i0 + 1 < N_) rp[i0 + 1] = off0 + c0;
  if (i0 + 2 < N_) rp[i0 + 2] = off0 + c0 + c1;
  if (i0 + 3 < N_) rp[i0 + 3] = off0 + c0 + c1 + c2;
}
__global__ void csr_fill_all_kernel(const int* __restrict__ edge_idx,
                                    const float* __restrict__ edge_w,
                                    const float* __restrict__ dinv,
                                    const int* __restrict__ rowptr, int* __restrict__ fill,
                                    int2* __restrict__ src_norm) {
  int e = blockIdx.x * blockDim.x + threadIdx.x;
  if (e < S_ * E_) {
    int s = e / E_;
    int ee = e - s * E_;
    int r = edge_idx[(size_t)s * 2 * E_ + ee];
    int c = edge_idx[(size_t)s * 2 * E_ + E_ + ee];
    float w = edge_w[(size_t)s * E_ + ee];
    int pos = rowptr[s * (N_ + 1) + c] + atomicAdd(&fill[s * N_ + c], 1);
    float nrm = dinv[s * N_ + r] * w * dinv[s * N_ + c];
    int2 pk; pk.x = r; pk.y = __float_as_int(nrm);
    src_norm[(size_t)s * E_ + pos] = pk;
  }
}

// ---------------------------------------------------------------------------
// Per-snapshot fused spmm+LN+ReLU, wave-per-edge gather (ushort4/lane).
// ---------------------------------------------------------------------------
__global__ __launch_bounds__(256) void spmm_ln_relu_kernel(
    const unsigned short* __restrict__ hW, const int* __restrict__ rowptr,
    const int2* __restrict__ src_norm,
    const float* __restrict__ dinv, const float* __restrict__ bgcn,
    const float* __restrict__ lnsc, const float* __restrict__ lnbi,
    unsigned short* __restrict__ out)
{
  __shared__ int s_src[256];
  __shared__ float s_nrm[256];
  __shared__ float s_acc[4][256];
  const int n = blockIdx.x;
  const int tid = threadIdx.x;
  const int lane = tid & 63, wv = tid >> 6;
  const int c4 = lane << 2;

  float a0 = 0.f, a1 = 0.f, a2 = 0.f, a3 = 0.f;
  const int e0 = rowptr[n], e1 = rowptr[n + 1];
  for (int base = e0; base < e1; base += 256) {
    int cnt = min(256, e1 - base);
    if (tid < cnt) {
      int2 pk = src_norm[base + tid];
      s_src[tid] = pk.x;
      s_nrm[tid] = __int_as_float(pk.y);
    }
    __syncthreads();
    int j = wv;
    for (; j + 12 < cnt; j += 16) {
      int r0 = s_src[j], r1 = s_src[j + 4], r2 = s_src[j + 8], r3 = s_src[j + 12];
      float n0 = s_nrm[j], n1 = s_nrm[j + 4], n2 = s_nrm[j + 8], n3 = s_nrm[j + 12];
      ushort4 u0 = *(const ushort4*)&hW[((size_t)r0 << 8) + c4];
      ushort4 u1 = *(const ushort4*)&hW[((size_t)r1 << 8) + c4];
      ushort4 u2 = *(const ushort4*)&hW[((size_t)r2 << 8) + c4];
      ushort4 u3 = *(const ushort4*)&hW[((size_t)r3 << 8) + c4];
      a0 = fmaf(n0, bf2f(u0.x), a0); a1 = fmaf(n0, bf2f(u0.y), a1);
      a2 = fmaf(n0, bf2f(u0.z), a2); a3 = fmaf(n0, bf2f(u0.w), a3);
      a0 = fmaf(n1, bf2f(u1.x), a0); a1 = fmaf(n1, bf2f(u1.y), a1);
      a2 = fmaf(n1, bf2f(u1.z), a2); a3 = fmaf(n1, bf2f(u1.w), a3);
      a0 = fmaf(n2, bf2f(u2.x), a0); a1 = fmaf(n2, bf2f(u2.y), a1);
      a2 = fmaf(n2, bf2f(u2.z), a2); a3 = fmaf(n2, bf2f(u2.w), a3);
      a0 = fmaf(n3, bf2f(u3.x), a0); a1 = fmaf(n3, bf2f(u3.y), a1);
      a2 = fmaf(n3, bf2f(u3.z), a2); a3 = fmaf(n3, bf2f(u3.w), a3);
    }
    for (; j < cnt; j += 4) {
      int r0 = s_src[j];
      float n0 = s_nrm[j];
      ushort4 u0 = *(const ushort4*)&hW[((size_t)r0 << 8) + c4];
      a0 = fmaf(n0, bf2f(u0.x), a0); a1 = fmaf(n0, bf2f(u0.y), a1);
      a2 = fmaf(n0, bf2f(u0.z), a2); a3 = fmaf(n0, bf2f(u0.w), a3);
    }
    __syncthreads();
  }
  s_acc[wv][c4 + 0] = a0; s_acc[wv][c4 + 1] = a1;
  s_acc[wv][c4 + 2] = a2; s_acc[wv][c4 + 3] = a3;
  __syncthreads();

  const int c = tid;
  float acc = (s_acc[0][c] + s_acc[1][c]) + (s_acc[2][c] + s_acc[3][c]);
  float dv = dinv[n];
  acc = fmaf(dv * dv, bf2f(hW[((size_t)n << 8) + c]), acc);   // self loop
  acc += bgcn[c];

  float s1 = acc, s2 = acc * acc;
  #pragma unroll
  for (int off = 32; off > 0; off >>= 1) {
    s1 += __shfl_down(s1, off);
    s2 += __shfl_down(s2, off);
  }
  __shared__ float r1[4], r2[4];
  if (lane == 0) { r1[wv] = s1; r2[wv] = s2; }
  __syncthreads();
  float t1 = r1[0] + r1[1] + r1[2] + r1[3];
  float t2 = r2[0] + r2[1] + r2[2] + r2[3];
  float mu = t1 * (1.0f / C_);
  float var = t2 * (1.0f / C_) - mu * mu;
  float inv = rsqrtf(var + EPS_);
  float v = (acc - mu) * inv * lnsc[c] + lnbi[c];
  out[((size_t)n << 8) + c] = f2bf(fmaxf(v, 0.f));
}

// ---------------------------------------------------------------------------
extern "C" void kernel_launch(void* const* d_in, const int* in_sizes, int n_in,
                              void* d_out, int out_size, void* d_ws, size_t ws_size,
                              hipStream_t stream) {
  const float* x        = (const float*)d_in[0];
  const int*   edge_idx = (const int*)d_in[1];
  const float* edge_w   = (const float*)d_in[2];
  const float* W_gcn    = (const float*)d_in[3];
  const float* b_gcn    = (const float*)d_in[4];
  const float* ln_scale = (const float*)d_in[5];
  const float* ln_bias  = (const float*)d_in[6];
  const float* w_ih     = (const float*)d_in[7];
  const float* w_hh     = (const float*)d_in[8];
  const float* b_ih     = (const float*)d_in[9];
  const float* b_hh     = (const float*)d_in[10];
  float* h_out = (float*)d_out;

  char* p = (char*)d_ws;
  auto carve = [&](size_t bytes) -> void* {
    void* r = (void*)p;
    p += (bytes + 255) & ~(size_t)255;
    return r;
  };
  unsigned long long* deg64 = (unsigned long long*)carve((size_t)S_ * N_ * 8);
  float* dinv        = (float*)carve((size_t)S_ * N_ * 4);
  int*   fill        = (int*)carve((size_t)S_ * N_ * 4);
  int*   rowptr      = (int*)carve((size_t)S_ * (N_ + 1) * 4);
  int*   chunk_sum   = (int*)carve((size_t)S_ * NCH_ * 4);
  int2*  src_norm    = (int2*)carve((size_t)S_ * E_ * 8);
  unsigned short* wt_gcn = (unsigned short*)carve((size_t)L_ * C_ * C_ * 2);
  unsigned short* wp_ih  = (unsigned short*)carve((size_t)768 * C_ * 2);
  unsigned short* wp_hh  = (unsigned short*)carve((size_t)768 * C_ * 2);
  unsigned short* xq_all = (unsigned short*)carve((size_t)S_ * N_ * C_ * 2);
  unsigned short* hW_all = (unsigned short*)carve((size_t)S_ * N_ * C_ * 2);
  unsigned short* fA_all = (unsigned short*)carve((size_t)S_ * N_ * C_ * 2);
  unsigned short* hq0    = (unsigned short*)carve((size_t)N_ * C_ * 2);
  unsigned short* hq1    = (unsigned short*)carve((size_t)N_ * C_ * 2);

  const int TB = 256;

  prep_wgcn_kernel<<<(L_ * C_ * C_ + TB - 1) / TB, TB, 0, stream>>>(W_gcn, wt_gcn);
  prep_wp_kernel<<<(768 * C_ + TB - 1) / TB, TB, 0, stream>>>(w_ih, wp_ih);
  prep_wp_kernel<<<(768 * C_ + TB - 1) / TB, TB, 0, stream>>>(w_hh, wp_hh);

  quant_kernel<<<((size_t)S_ * N_ * C_ / 4 + TB - 1) / TB, TB, 0, stream>>>(
      x, xq_all, S_ * N_ * C_ / 4);

  init_kernel<<<(S_ * N_ + TB - 1) / TB, TB, 0, stream>>>(deg64, fill, S_ * N_);
  deg_count_all_kernel<<<(S_ * E_ + TB - 1) / TB, TB, 0, stream>>>(edge_idx, edge_w, deg64);
  dinv_kernel<<<(S_ * N_ + TB - 1) / TB, TB, 0, stream>>>(deg64, dinv, S_ * N_);
  chunk_sum_kernel<<<S_ * NCH_, TB, 0, stream>>>(deg64, chunk_sum);
  scan_chunks_kernel<<<1, 64, 0, stream>>>(chunk_sum, rowptr);
  scan_final_kernel<<<S_ * NCH_, TB, 0, stream>>>(deg64, chunk_sum, rowptr);
  csr_fill_all_kernel<<<(S_ * E_ + TB - 1) / TB, TB, 0, stream>>>(
      edge_idx, edge_w, dinv, rowptr, fill, src_norm);

  // GCN layers: GEMM batched over snapshots (swizzled grid); spmm per snapshot
  const int M_all = S_ * N_;
  const int nbx = (M_all + 127) / 128;
  {
    const unsigned short* hin = xq_all;
    for (int l = 0; l < L_; ++l) {
      unsigned short* fout = (l == 1) ? xq_all : fA_all;
      gemm_bf16_kernel<<<nbx * (C_ / 128), 256, 0, stream>>>(
          hin, wt_gcn + (size_t)l * C_ * C_, hW_all, M_all, C_, C_, C_ / 128);
      for (int s = 0; s < S_; ++s) {
        spmm_ln_relu_kernel<<<N_, 256, 0, stream>>>(
            hW_all + (size_t)s * N_ * C_, rowptr + s * (N_ + 1),
            src_norm + (size_t)s * E_,
            dinv + s * N_, b_gcn + l * C_,
            ln_scale + l * C_, ln_bias + l * C_, fout + (size_t)s * N_ * C_);
      }
      hin = fout;
    }
  }
  const unsigned short* feat_all = fA_all;

  // Fused GRU recurrence (hq ping-pong, bf16 carry; fp32 out on last step)
  const int gnb = ((N_ + 127) / 128) * 8;
  unsigned short* hq_cur = hq0;
  unsigned short* hq_nxt = hq1;
  for (int s = 0; s < S_; ++s) {
    bool last = (s == S_ - 1);
    gru_fused_kernel<<<gnb, 256, 0, stream>>>(
        feat_all + (size_t)s * N_ * C_,
        hq_cur,                     // unused when first
        wp_ih, wp_hh, b_ih, b_hh,
        last ? nullptr : hq_nxt,
        last ? h_out : nullptr,
        (s == 0) ? 1 : 0, N_);
    unsigned short* t = hq_cur; hq_cur = hq_nxt; hq_nxt = t;
  }
}

// Round 8
// 1678.371 us; speedup vs baseline: 3.9041x; 1.1842x over previous
//
#include <hip/hip_runtime.h>
#include <cmath>

#define S_ 4
#define N_ 50000
#define C_ 256
#define E_ 800000
#define L_ 3
#define EPS_ 1e-5f
#define NCH_ ((N_ + 1023) / 1024)

typedef __attribute__((ext_vector_type(8))) short bf16x8;
typedef __attribute__((ext_vector_type(4))) float f32x4;

__device__ __forceinline__ float bf2f(unsigned short s) {
  return __uint_as_float(((unsigned)s) << 16);
}
__device__ __forceinline__ unsigned short f2bf(float f) {
  unsigned u = __float_as_uint(f);
  return (unsigned short)((u + 0x7fffu + ((u >> 16) & 1u)) >> 16);  // RNE
}

__device__ __forceinline__ void gload_lds16(const void* g, void* l) {
  __builtin_amdgcn_global_load_lds(
      (const __attribute__((address_space(1))) unsigned int*)g,
      (__attribute__((address_space(3))) unsigned int*)l, 16, 0, 0);
}

// bijective XCD-aware panel swizzle: 1D id -> (bmi, bni), bni fastest within
// groups of 8 bm so same-bm blocks share an XCD L2 (blockIdx round-robins %8).
__device__ __forceinline__ void swz_block(int id, int nbx, int nby, int& bmi, int& bni) {
  const int NB8 = nby * 8;
  int fullb = (nbx >> 3) * NB8;
  if (id < fullb) {
    int g = id / NB8, pp = id - g * NB8;
    bmi = g * 8 + (pp & 7);
    bni = pp >> 3;
  } else {
    int rem = nbx & 7;
    int idp = id - fullb;
    bmi = (nbx & ~7) + idp % rem;
    bni = idp / rem;
  }
}

// ---------------------------------------------------------------------------
// bf16 MFMA GEMM: Cout[M,Nn] = A[M,K](bf16) * Bt[Nn,K]^T(bf16), bf16 out.
// 128x128 tile, BK=32, 256 threads, 2-phase dbuf LDS, swizzled 1D grid.
// ---------------------------------------------------------------------------
__global__ __launch_bounds__(256) void gemm_bf16_kernel(
    const unsigned short* __restrict__ A, const unsigned short* __restrict__ Bt,
    unsigned short* __restrict__ Cout, int M, int Nn, int K, int nby)
{
  __shared__ alignas(16) unsigned short As[2][128 * 32];
  __shared__ alignas(16) unsigned short Bs[2][128 * 32];
  const int tid = threadIdx.x;
  const int lane = tid & 63;
  const int wid = tid >> 6;
  const int wr = wid >> 1, wc = wid & 1;
  int bmi, bni;
  swz_block(blockIdx.x, gridDim.x / nby, nby, bmi, bni);
  const int bm = bmi * 128, bn = bni * 128;
  const int l15 = lane & 15, l4 = lane >> 4;

  f32x4 acc[4][4] = {};

  int offA[4], offB[4];
  #pragma unroll
  for (int mi = 0; mi < 4; ++mi) {
    int ra = wr * 64 + mi * 16 + l15;
    offA[mi] = ra * 32 + ((l4 ^ ((ra >> 1) & 3)) << 3);
    int rb = wc * 64 + mi * 16 + l15;
    offB[mi] = rb * 32 + ((l4 ^ ((rb >> 1) & 3)) << 3);
  }
  const int rs = tid >> 2;
  const int gs = tid & 3;

  auto stage = [&](int buf, int k0) {
    #pragma unroll
    for (int t2 = 0; t2 < 2; ++t2) {
      int r = rs + t2 * 64;
      int q = gs ^ ((r >> 1) & 3);
      int arow = bm + r; if (arow >= M) arow = M - 1;
      gload_lds16(&A[(size_t)arow * K + k0 + q * 8], &As[buf][(t2 * 256 + tid) * 8]);
      int brow = bn + r;
      gload_lds16(&Bt[(size_t)brow * K + k0 + q * 8], &Bs[buf][(t2 * 256 + tid) * 8]);
    }
  };

  const int nt = K >> 5;
  stage(0, 0);
  asm volatile("s_waitcnt vmcnt(0)" ::: "memory");
  __syncthreads();

  int cur = 0;
  for (int t = 0; t < nt; ++t) {
    if (t + 1 < nt) stage(cur ^ 1, (t + 1) * 32);

    bf16x8 af[4], bfr[4];
    #pragma unroll
    for (int mi = 0; mi < 4; ++mi) af[mi] = *(const bf16x8*)&As[cur][offA[mi]];
    #pragma unroll
    for (int ni = 0; ni < 4; ++ni) bfr[ni] = *(const bf16x8*)&Bs[cur][offB[ni]];
    #pragma unroll
    for (int mi = 0; mi < 4; ++mi)
      #pragma unroll
      for (int ni = 0; ni < 4; ++ni)
        acc[mi][ni] = __builtin_amdgcn_mfma_f32_16x16x32_bf16(
            af[mi], bfr[ni], acc[mi][ni], 0, 0, 0);

    asm volatile("s_waitcnt vmcnt(0)" ::: "memory");
    __syncthreads();
    cur ^= 1;
  }

  #pragma unroll
  for (int mi = 0; mi < 4; ++mi) {
    int rowb = bm + wr * 64 + mi * 16 + l4 * 4;
    #pragma unroll
    for (int ni = 0; ni < 4; ++ni) {
      int col = bn + wc * 64 + ni * 16 + l15;
      #pragma unroll
      for (int r = 0; r < 4; ++r) {
        int row = rowb + r;
        if (row < M) Cout[(size_t)row * Nn + col] = f2bf(acc[mi][ni][r]);
      }
    }
  }
}

// ---------------------------------------------------------------------------
// Fused GRU step: gates = feat*W_ih^T (+) hq*W_hh^T, epilogue does
// r/z/n + h update, writes bf16 hq_out (and fp32 hout on last step).
// Wp_* prepacked [8 chunks][96 rows = gate*32+dc][256 k].
// ---------------------------------------------------------------------------
__global__ __launch_bounds__(256) void gru_fused_kernel(
    const unsigned short* __restrict__ feat,
    const unsigned short* __restrict__ hq_in,
    const unsigned short* __restrict__ Wp_ih,
    const unsigned short* __restrict__ Wp_hh,
    const float* __restrict__ b_ih, const float* __restrict__ b_hh,
    unsigned short* __restrict__ hq_out, float* __restrict__ hout,
    int first, int M)
{
  __shared__ alignas(16) unsigned short As[2][128 * 32];
  __shared__ alignas(16) unsigned short Bs[2][96 * 32];
  const int tid = threadIdx.x;
  const int lane = tid & 63;
  const int wv = tid >> 6;
  const int l15 = lane & 15, l4 = lane >> 4;

  int bmi, bni;
  swz_block(blockIdx.x, gridDim.x / 8, 8, bmi, bni);
  const int bm = bmi * 128;
  const int c0 = bni * 32;
  const int brow0 = bni * 96;

  f32x4 acc_i[2][6] = {};
  f32x4 acc_h[2][6] = {};

  int offA[2], offB[6];
  #pragma unroll
  for (int mi = 0; mi < 2; ++mi) {
    int ra = wv * 32 + mi * 16 + l15;
    offA[mi] = ra * 32 + ((l4 ^ ((ra >> 1) & 3)) << 3);
  }
  #pragma unroll
  for (int ni = 0; ni < 6; ++ni) {
    int rb = ni * 16 + l15;
    offB[ni] = rb * 32 + ((l4 ^ ((rb >> 1) & 3)) << 3);
  }

  const int nt = first ? 8 : 16;

  auto stage = [&](int buf, int t) {
    int k0 = (t & 7) * 32;
    const unsigned short* Ap = (t < 8) ? feat : hq_in;
    const unsigned short* Bp = (t < 8) ? Wp_ih : Wp_hh;
    #pragma unroll
    for (int t2 = 0; t2 < 2; ++t2) {
      int slot = t2 * 256 + tid;
      int r = slot >> 2;
      int q = (slot & 3) ^ ((r >> 1) & 3);
      int arow = bm + r; if (arow >= M) arow = M - 1;
      gload_lds16(&Ap[(size_t)arow * 256 + k0 + q * 8], &As[buf][slot * 8]);
    }
    {
      int slot = tid;
      int r = slot >> 2;
      int q = (slot & 3) ^ ((r >> 1) & 3);
      gload_lds16(&Bp[(size_t)(brow0 + r) * 256 + k0 + q * 8], &Bs[buf][slot * 8]);
    }
    if (tid < 128) {
      int slot = 256 + tid;
      int r = slot >> 2;
      int q = (slot & 3) ^ ((r >> 1) & 3);
      gload_lds16(&Bp[(size_t)(brow0 + r) * 256 + k0 + q * 8], &Bs[buf][slot * 8]);
    }
  };

  stage(0, 0);
  asm volatile("s_waitcnt vmcnt(0)" ::: "memory");
  __syncthreads();

  int cur = 0;
  for (int t = 0; t < nt; ++t) {
    if (t + 1 < nt) stage(cur ^ 1, t + 1);

    bf16x8 af[2], bfr[6];
    #pragma unroll
    for (int mi = 0; mi < 2; ++mi) af[mi] = *(const bf16x8*)&As[cur][offA[mi]];
    #pragma unroll
    for (int ni = 0; ni < 6; ++ni) bfr[ni] = *(const bf16x8*)&Bs[cur][offB[ni]];
    if (t < 8) {
      #pragma unroll
      for (int mi = 0; mi < 2; ++mi)
        #pragma unroll
        for (int ni = 0; ni < 6; ++ni)
          acc_i[mi][ni] = __builtin_amdgcn_mfma_f32_16x16x32_bf16(
              af[mi], bfr[ni], acc_i[mi][ni], 0, 0, 0);
    } else {
      #pragma unroll
      for (int mi = 0; mi < 2; ++mi)
        #pragma unroll
        for (int ni = 0; ni < 6; ++ni)
          acc_h[mi][ni] = __builtin_amdgcn_mfma_f32_16x16x32_bf16(
              af[mi], bfr[ni], acc_h[mi][ni], 0, 0, 0);
    }

    asm volatile("s_waitcnt vmcnt(0)" ::: "memory");
    __syncthreads();
    cur ^= 1;
  }

  #pragma unroll
  for (int cni = 0; cni < 2; ++cni) {
    int c = c0 + cni * 16 + l15;
    float bir = b_ih[c], biz = b_ih[256 + c], bin = b_ih[512 + c];
    float bhr = b_hh[c], bhz = b_hh[256 + c], bhn = b_hh[512 + c];
    #pragma unroll
    for (int mi = 0; mi < 2; ++mi) {
      int rowb = bm + wv * 32 + mi * 16 + l4 * 4;
      #pragma unroll
      for (int rr = 0; rr < 4; ++rr) {
        int row = rowb + rr;
        if (row < M) {
          float gir = acc_i[mi][0 + cni][rr] + bir;
          float ghr = acc_h[mi][0 + cni][rr] + bhr;
          float giz = acc_i[mi][2 + cni][rr] + biz;
          float ghz = acc_h[mi][2 + cni][rr] + bhz;
          float gin = acc_i[mi][4 + cni][rr] + bin;
          float ghn = acc_h[mi][4 + cni][rr] + bhn;
          float rg = 1.f / (1.f + expf(-(gir + ghr)));
          float zg = 1.f / (1.f + expf(-(giz + ghz)));
          float ng = tanhf(gin + rg * ghn);
          float hp = first ? 0.f : bf2f(hq_in[(size_t)row * 256 + c]);
          float hv = (1.f - zg) * ng + zg * hp;
          if (hq_out) hq_out[(size_t)row * 256 + c] = f2bf(hv);
          if (hout) hout[(size_t)row * 256 + c] = hv;
        }
      }
    }
  }
}

// ---------------------------------------------------------------------------
// Weight prep
// ---------------------------------------------------------------------------
__global__ void prep_wgcn_kernel(const float* __restrict__ W, unsigned short* __restrict__ Wt) {
  int i = blockIdx.x * blockDim.x + threadIdx.x;  // l*C*C + n*C + k
  if (i < L_ * C_ * C_) {
    int l = i / (C_ * C_);
    int rem = i - l * C_ * C_;
    int nn = rem >> 8, k = rem & 255;
    Wt[i] = f2bf(W[l * C_ * C_ + k * C_ + nn]);
  }
}
// pack [768,256] gate-major per 32-channel chunk: row chunk*96 + g*32 + dc
__global__ void prep_wp_kernel(const float* __restrict__ W, unsigned short* __restrict__ Wp) {
  int d = blockIdx.x * blockDim.x + threadIdx.x;
  if (d < 768 * 256) {
    int jrow = d >> 8, k = d & 255;
    int chunk = jrow / 96, j = jrow - chunk * 96;
    int g = j >> 5, dc = j & 31;
    int srow = g * 256 + chunk * 32 + dc;
    Wp[d] = f2bf(W[srow * 256 + k]);
  }
}
__global__ void quant_kernel(const float* __restrict__ in, unsigned short* __restrict__ out, int n4) {
  int i = blockIdx.x * blockDim.x + threadIdx.x;
  if (i < n4) {
    float4 v = ((const float4*)in)[i];
    ushort4 q;
    q.x = f2bf(v.x); q.y = f2bf(v.y); q.z = f2bf(v.z); q.w = f2bf(v.w);
    *(ushort4*)&out[i * 4] = q;
  }
}

// ---------------------------------------------------------------------------
// Graph preprocessing: deg+cnt packed u64 (cnt bits[40:64), fixed-point deg)
// ---------------------------------------------------------------------------
__global__ void init_kernel(unsigned long long* __restrict__ deg64,
                            int* __restrict__ fill, int n) {
  int i = blockIdx.x * blockDim.x + threadIdx.x;
  if (i < n) { deg64[i] = (1ULL << 20); fill[i] = 0; }
}
__global__ void deg_count_all_kernel(const int* __restrict__ edge_idx,
                                     const float* __restrict__ edge_w,
                                     unsigned long long* __restrict__ deg64) {
  int e = blockIdx.x * blockDim.x + threadIdx.x;
  if (e < S_ * E_) {
    int s = e / E_;
    int ee = e - s * E_;
    int c = edge_idx[(size_t)s * 2 * E_ + E_ + ee];
    float w = edge_w[(size_t)s * E_ + ee];
    unsigned long long q = (unsigned long long)__float2uint_rn(w * 1048576.0f);
    atomicAdd(&deg64[s * N_ + c], q + (1ULL << 40));
  }
}
__global__ void dinv_kernel(const unsigned long long* __restrict__ deg64,
                            float* __restrict__ dinv, int n) {
  int i = blockIdx.x * blockDim.x + threadIdx.x;
  if (i < n) {
    float d = (float)(deg64[i] & ((1ULL << 40) - 1)) * (1.0f / 1048576.0f);
    dinv[i] = rsqrtf(fmaxf(d, 1e-12f));
  }
}
__global__ void chunk_sum_kernel(const unsigned long long* __restrict__ deg64,
                                 int* __restrict__ chunk_sum) {
  int b = blockIdx.x;
  int s = b / NCH_, ch = b - s * NCH_;
  const unsigned long long* dg = deg64 + (size_t)s * N_;
  int base = ch * 1024 + threadIdx.x * 4;
  int v = 0;
  #pragma unroll
  for (int j = 0; j < 4; ++j)
    if (base + j < N_) v += (int)(dg[base + j] >> 40);
  #pragma unroll
  for (int off = 32; off > 0; off >>= 1) v += __shfl_down(v, off);
  __shared__ int ws[4];
  int lane = threadIdx.x & 63, wv = threadIdx.x >> 6;
  if (lane == 0) ws[wv] = v;
  __syncthreads();
  if (threadIdx.x == 0) chunk_sum[s * NCH_ + ch] = ws[0] + ws[1] + ws[2] + ws[3];
}
__global__ void scan_chunks_kernel(int* __restrict__ chunk_sum, int* __restrict__ rowptr) {
  int s = threadIdx.x;
  if (s < S_) {
    int tot = 0;
    for (int ch = 0; ch < NCH_; ++ch) {
      int t = chunk_sum[s * NCH_ + ch];
      chunk_sum[s * NCH_ + ch] = tot;
      tot += t;
    }
    rowptr[s * (N_ + 1) + N_] = tot;
  }
}
__global__ void scan_final_kernel(const unsigned long long* __restrict__ deg64,
                                  const int* __restrict__ chunk_sum,
                                  int* __restrict__ rowptr) {
  int b = blockIdx.x;
  int s = b / NCH_, ch = b - s * NCH_;
  const unsigned long long* dg = deg64 + (size_t)s * N_;
  int t = threadIdx.x;
  int i0 = ch * 1024 + t * 4;
  int c0 = 0, c1 = 0, c2 = 0, c3 = 0;
  if (i0 + 0 < N_) c0 = (int)(dg[i0 + 0] >> 40);
  if (i0 + 1 < N_) c1 = (int)(dg[i0 + 1] >> 40);
  if (i0 + 2 < N_) c2 = (int)(dg[i0 + 2] >> 40);
  if (i0 + 3 < N_) c3 = (int)(dg[i0 + 3] >> 40);
  int tsum = c0 + c1 + c2 + c3;
  int lane = t & 63, wv = t >> 6;
  int inc = tsum;
  #pragma unroll
  for (int off = 1; off < 64; off <<= 1) {
    int u = __shfl_up(inc, off);
    if (lane >= off) inc += u;
  }
  __shared__ int ws[4];
  if (lane == 63) ws[wv] = inc;
  __syncthreads();
  int woff = 0;
  for (int k = 0; k < 4; ++k) if (k < wv) woff += ws[k];
  int off0 = chunk_sum[s * NCH_ + ch] + woff + inc - tsum;
  int* rp = rowptr + (size_t)s * (N_ + 1);
  if (i0 + 0 < N_) rp[i0 + 0] = off0;
  if (i0 + 1 < N_) rp[i0 + 1] = off0 + c0;
  if (i0 + 2 < N_) rp[i0 + 2] = off0 + c0 + c1;
  if (i0 + 3 < N_) rp[i0 + 3] = off0 + c0 + c1 + c2;
}
// 4B packed record: src (16 bits) | bf16(norm) << 16
__global__ void csr_fill_all_kernel(const int* __restrict__ edge_idx,
                                    const float* __restrict__ edge_w,
                                    const float* __restrict__ dinv,
                                    const int* __restrict__ rowptr, int* __restrict__ fill,
                                    unsigned int* __restrict__ src_norm) {
  int e = blockIdx.x * blockDim.x + threadIdx.x;
  if (e < S_ * E_) {
    int s = e / E_;
    int ee = e - s * E_;
    int r = edge_idx[(size_t)s * 2 * E_ + ee];
    int c = edge_idx[(size_t)s * 2 * E_ + E_ + ee];
    float w = edge_w[(size_t)s * E_ + ee];
    int pos = rowptr[s * (N_ + 1) + c] + atomicAdd(&fill[s * N_ + c], 1);
    float nrm = dinv[s * N_ + r] * w * dinv[s * N_ + c];
    unsigned int rec = (unsigned int)r | ((unsigned int)f2bf(nrm) << 16);
    src_norm[(size_t)s * E_ + pos] = rec;
  }
}

// ---------------------------------------------------------------------------
// Per-snapshot fused spmm+LN+ReLU. WAVE-PER-NODE: lane owns 4 channels;
// wave's 64 lanes fetch a full 512B row per edge. Edge records preloaded
// 64/chunk into a register, broadcast via __shfl. No LDS, no barriers.
// ---------------------------------------------------------------------------
__global__ __launch_bounds__(256) void spmm_ln_relu_kernel(
    const unsigned short* __restrict__ hW, const int* __restrict__ rowptr,
    const unsigned int* __restrict__ src_norm,
    const float* __restrict__ dinv, const float* __restrict__ bgcn,
    const float* __restrict__ lnsc, const float* __restrict__ lnbi,
    unsigned short* __restrict__ out)
{
  const int tid = threadIdx.x;
  const int lane = tid & 63, wv = tid >> 6;
  const int n = blockIdx.x * 4 + wv;
  const int c4 = lane << 2;

  float a0, a1, a2, a3;
  {
    float dv = dinv[n];
    float w = dv * dv;
    ushort4 u = *(const ushort4*)&hW[((size_t)n << 8) + c4];
    a0 = w * bf2f(u.x); a1 = w * bf2f(u.y); a2 = w * bf2f(u.z); a3 = w * bf2f(u.w);
  }
  const int e0 = rowptr[n], e1 = rowptr[n + 1];
  for (int base = e0; base < e1; base += 64) {
    int cnt = min(64, e1 - base);
    unsigned int rec = (base + lane < e1) ? src_norm[base + lane] : 0u;
    int j = 0;
    for (; j + 3 < cnt; j += 4) {
      unsigned int r0 = __shfl((int)rec, j + 0);
      unsigned int r1 = __shfl((int)rec, j + 1);
      unsigned int r2 = __shfl((int)rec, j + 2);
      unsigned int r3 = __shfl((int)rec, j + 3);
      ushort4 u0 = *(const ushort4*)&hW[((size_t)(r0 & 0xFFFFu) << 8) + c4];
      ushort4 u1 = *(const ushort4*)&hW[((size_t)(r1 & 0xFFFFu) << 8) + c4];
      ushort4 u2 = *(const ushort4*)&hW[((size_t)(r2 & 0xFFFFu) << 8) + c4];
      ushort4 u3 = *(const ushort4*)&hW[((size_t)(r3 & 0xFFFFu) << 8) + c4];
      float n0 = bf2f((unsigned short)(r0 >> 16));
      float n1 = bf2f((unsigned short)(r1 >> 16));
      float n2 = bf2f((unsigned short)(r2 >> 16));
      float n3 = bf2f((unsigned short)(r3 >> 16));
      a0 = fmaf(n0, bf2f(u0.x), a0); a1 = fmaf(n0, bf2f(u0.y), a1);
      a2 = fmaf(n0, bf2f(u0.z), a2); a3 = fmaf(n0, bf2f(u0.w), a3);
      a0 = fmaf(n1, bf2f(u1.x), a0); a1 = fmaf(n1, bf2f(u1.y), a1);
      a2 = fmaf(n1, bf2f(u1.z), a2); a3 = fmaf(n1, bf2f(u1.w), a3);
      a0 = fmaf(n2, bf2f(u2.x), a0); a1 = fmaf(n2, bf2f(u2.y), a1);
      a2 = fmaf(n2, bf2f(u2.z), a2); a3 = fmaf(n2, bf2f(u2.w), a3);
      a0 = fmaf(n3, bf2f(u3.x), a0); a1 = fmaf(n3, bf2f(u3.y), a1);
      a2 = fmaf(n3, bf2f(u3.z), a2); a3 = fmaf(n3, bf2f(u3.w), a3);
    }
    for (; j < cnt; ++j) {
      unsigned int r0 = __shfl((int)rec, j);
      ushort4 u0 = *(const ushort4*)&hW[((size_t)(r0 & 0xFFFFu) << 8) + c4];
      float n0 = bf2f((unsigned short)(r0 >> 16));
      a0 = fmaf(n0, bf2f(u0.x), a0); a1 = fmaf(n0, bf2f(u0.y), a1);
      a2 = fmaf(n0, bf2f(u0.z), a2); a3 = fmaf(n0, bf2f(u0.w), a3);
    }
  }

  float4 bg = *(const float4*)&bgcn[c4];
  float v0 = a0 + bg.x, v1 = a1 + bg.y, v2 = a2 + bg.z, v3 = a3 + bg.w;
  float s1 = (v0 + v1) + (v2 + v3);
  float s2 = (v0 * v0 + v1 * v1) + (v2 * v2 + v3 * v3);
  #pragma unroll
  for (int off = 32; off > 0; off >>= 1) {
    s1 += __shfl_xor(s1, off);
    s2 += __shfl_xor(s2, off);
  }
  float mu = s1 * (1.0f / C_);
  float var = s2 * (1.0f / C_) - mu * mu;
  float inv = rsqrtf(var + EPS_);
  float4 sc = *(const float4*)&lnsc[c4];
  float4 bi = *(const float4*)&lnbi[c4];
  ushort4 o;
  o.x = f2bf(fmaxf((v0 - mu) * inv * sc.x + bi.x, 0.f));
  o.y = f2bf(fmaxf((v1 - mu) * inv * sc.y + bi.y, 0.f));
  o.z = f2bf(fmaxf((v2 - mu) * inv * sc.z + bi.z, 0.f));
  o.w = f2bf(fmaxf((v3 - mu) * inv * sc.w + bi.w, 0.f));
  *(ushort4*)&out[((size_t)n << 8) + c4] = o;
}

// ---------------------------------------------------------------------------
extern "C" void kernel_launch(void* const* d_in, const int* in_sizes, int n_in,
                              void* d_out, int out_size, void* d_ws, size_t ws_size,
                              hipStream_t stream) {
  const float* x        = (const float*)d_in[0];
  const int*   edge_idx = (const int*)d_in[1];
  const float* edge_w   = (const float*)d_in[2];
  const float* W_gcn    = (const float*)d_in[3];
  const float* b_gcn    = (const float*)d_in[4];
  const float* ln_scale = (const float*)d_in[5];
  const float* ln_bias  = (const float*)d_in[6];
  const float* w_ih     = (const float*)d_in[7];
  const float* w_hh     = (const float*)d_in[8];
  const float* b_ih     = (const float*)d_in[9];
  const float* b_hh     = (const float*)d_in[10];
  float* h_out = (float*)d_out;

  char* p = (char*)d_ws;
  auto carve = [&](size_t bytes) -> void* {
    void* r = (void*)p;
    p += (bytes + 255) & ~(size_t)255;
    return r;
  };
  unsigned long long* deg64 = (unsigned long long*)carve((size_t)S_ * N_ * 8);
  float* dinv        = (float*)carve((size_t)S_ * N_ * 4);
  int*   fill        = (int*)carve((size_t)S_ * N_ * 4);
  int*   rowptr      = (int*)carve((size_t)S_ * (N_ + 1) * 4);
  int*   chunk_sum   = (int*)carve((size_t)S_ * NCH_ * 4);
  unsigned int* src_norm = (unsigned int*)carve((size_t)S_ * E_ * 4);
  unsigned short* wt_gcn = (unsigned short*)carve((size_t)L_ * C_ * C_ * 2);
  unsigned short* wp_ih  = (unsigned short*)carve((size_t)768 * C_ * 2);
  unsigned short* wp_hh  = (unsigned short*)carve((size_t)768 * C_ * 2);
  unsigned short* xq_all = (unsigned short*)carve((size_t)S_ * N_ * C_ * 2);
  unsigned short* hW_all = (unsigned short*)carve((size_t)S_ * N_ * C_ * 2);
  unsigned short* fA_all = (unsigned short*)carve((size_t)S_ * N_ * C_ * 2);
  unsigned short* hq0    = (unsigned short*)carve((size_t)N_ * C_ * 2);
  unsigned short* hq1    = (unsigned short*)carve((size_t)N_ * C_ * 2);

  const int TB = 256;

  prep_wgcn_kernel<<<(L_ * C_ * C_ + TB - 1) / TB, TB, 0, stream>>>(W_gcn, wt_gcn);
  prep_wp_kernel<<<(768 * C_ + TB - 1) / TB, TB, 0, stream>>>(w_ih, wp_ih);
  prep_wp_kernel<<<(768 * C_ + TB - 1) / TB, TB, 0, stream>>>(w_hh, wp_hh);

  quant_kernel<<<((size_t)S_ * N_ * C_ / 4 + TB - 1) / TB, TB, 0, stream>>>(
      x, xq_all, S_ * N_ * C_ / 4);

  init_kernel<<<(S_ * N_ + TB - 1) / TB, TB, 0, stream>>>(deg64, fill, S_ * N_);
  deg_count_all_kernel<<<(S_ * E_ + TB - 1) / TB, TB, 0, stream>>>(edge_idx, edge_w, deg64);
  dinv_kernel<<<(S_ * N_ + TB - 1) / TB, TB, 0, stream>>>(deg64, dinv, S_ * N_);
  chunk_sum_kernel<<<S_ * NCH_, TB, 0, stream>>>(deg64, chunk_sum);
  scan_chunks_kernel<<<1, 64, 0, stream>>>(chunk_sum, rowptr);
  scan_final_kernel<<<S_ * NCH_, TB, 0, stream>>>(deg64, chunk_sum, rowptr);
  csr_fill_all_kernel<<<(S_ * E_ + TB - 1) / TB, TB, 0, stream>>>(
      edge_idx, edge_w, dinv, rowptr, fill, src_norm);

  // GCN layers: GEMM batched over snapshots (swizzled grid); spmm per snapshot
  const int M_all = S_ * N_;
  const int nbx = (M_all + 127) / 128;
  {
    const unsigned short* hin = xq_all;
    for (int l = 0; l < L_; ++l) {
      unsigned short* fout = (l == 1) ? xq_all : fA_all;
      gemm_bf16_kernel<<<nbx * (C_ / 128), 256, 0, stream>>>(
          hin, wt_gcn + (size_t)l * C_ * C_, hW_all, M_all, C_, C_, C_ / 128);
      for (int s = 0; s < S_; ++s) {
        spmm_ln_relu_kernel<<<N_ / 4, 256, 0, stream>>>(
            hW_all + (size_t)s * N_ * C_, rowptr + s * (N_ + 1),
            src_norm + (size_t)s * E_,
            dinv + s * N_, b_gcn + l * C_,
            ln_scale + l * C_, ln_bias + l * C_, fout + (size_t)s * N_ * C_);
      }
      hin = fout;
    }
  }
  const unsigned short* feat_all = fA_all;

  // Fused GRU recurrence (hq ping-pong, bf16 carry; fp32 out on last step)
  const int gnb = ((N_ + 127) / 128) * 8;
  unsigned short* hq_cur = hq0;
  unsigned short* hq_nxt = hq1;
  for (int s = 0; s < S_; ++s) {
    bool last = (s == S_ - 1);
    gru_fused_kernel<<<gnb, 256, 0, stream>>>(
        feat_all + (size_t)s * N_ * C_,
        hq_cur,
        wp_ih, wp_hh, b_ih, b_hh,
        last ? nullptr : hq_nxt,
        last ? h_out : nullptr,
        (s == 0) ? 1 : 0, N_);
    unsigned short* t = hq_cur; hq_cur = hq_nxt; hq_nxt = t;
  }
}